// Round 3
// baseline (1490.632 us; speedup 1.0000x reference)
//
#include <hip/hip_runtime.h>
#include <math.h>

#define N_NODES 65536
#define N_EDGES 262144
#define N_LAYERS 6
#define T_MAX_F 16.0f
#define EPS_F 1e-5f

typedef float  f32x4  __attribute__((ext_vector_type(4)));
typedef __bf16 bf16x8 __attribute__((ext_vector_type(8)));
typedef __bf16 bf16x4 __attribute__((ext_vector_type(4)));

__device__ __forceinline__ float silu_f(float v){
    return v / (1.0f + __expf(-v));
}

__device__ __forceinline__ f32x4 mfma16(bf16x8 a, bf16x8 b, f32x4 c){
    return __builtin_amdgcn_mfma_f32_16x16x32_bf16(a, b, c, 0, 0, 0);
}

// A-fragment LDS halfword index, M=32 tiles (2 row-tiles):
__device__ __forceinline__ int apos(int row, int k){
    return (((k >> 5) * 2 + (row >> 4)) * 64 + ((row & 15) | (((k >> 3) & 3) << 4))) * 8 + (k & 7);
}

// ---------------- weight prepack ----------------
// B-fragment packed layout per weight: [kb][cb][lane(64)][elem(8)],
// col = cb*16 + (lane&15), k = kb*32 + (lane>>4)*8 + elem.
#define PK_RA (6 * 20480)   // msg W1 dst-side, K=160 (5 kb), 128 cols
#define PK_RB (6 * 20480)   // msg W1 src-side
#define PK_M2 (6 * 16384)   // msg W2, K=128
#define PK_U1 (6 * 36864)   // upd W1, K=288 pad
#define PK_U2 (6 * 16384)   // upd W2, K=128
#define PK_TOTAL (PK_RA + PK_RB + PK_M2 + PK_U1 + PK_U2)

__global__ __launch_bounds__(256) void k_pack(const float* __restrict__ msgW1, const float* __restrict__ msgW2,
                                              const float* __restrict__ updW1, const float* __restrict__ updW2,
                                              __bf16* __restrict__ out){
    int pg = blockIdx.x * 256 + threadIdx.x;
    if (pg >= PK_TOTAL) return;
    int p = pg;
    int mode; const float* W; int perL;
    if (p < PK_RA){ mode = 0; W = msgW1; perL = 20480; }
    else if ((p -= PK_RA) < PK_RB){ mode = 1; W = msgW1; perL = 20480; }
    else if ((p -= PK_RB) < PK_M2){ mode = 2; W = msgW2; perL = 16384; }
    else if ((p -= PK_M2) < PK_U1){ mode = 3; W = updW1; perL = 36864; }
    else { p -= PK_U1; mode = 4; W = updW2; perL = 16384; }
    int l = p / perL, q = p % perL;
    int elem = q & 7, lane = (q >> 3) & 63, cb = (q >> 9) & 7, kb = q >> 12;
    int col = cb * 16 + (lane & 15);
    int k = kb * 32 + ((lane >> 4) << 3) + elem;
    float v = 0.0f;
    if (mode == 0){
        // ra: rows [h_dst(0:128) | xdiff(256:281) | pdiff(281) | vars(282:286)]
        int r = -1;
        if (k < 128) r = k;
        else if (k < 153) r = 256 + (k - 128);
        else if (k == 153) r = 281;
        else if (k < 158) r = 282 + (k - 154);
        if (r >= 0) v = W[(size_t)l * 286 * 128 + (size_t)r * 128 + col];
    } else if (mode == 1){
        // rb: rows [h_src(128:256) | -xdiff | -pdiff]
        if (k < 128) v = W[(size_t)l * 286 * 128 + (size_t)(128 + k) * 128 + col];
        else if (k < 153) v = -W[(size_t)l * 286 * 128 + (size_t)(256 + (k - 128)) * 128 + col];
        else if (k == 153) v = -W[(size_t)l * 286 * 128 + (size_t)281 * 128 + col];
    } else {
        int Kreal = (mode == 3) ? 260 : 128;
        if (k < Kreal) v = W[(size_t)l * Kreal * 128 + (size_t)k * 128 + col];
    }
    out[pg] = (__bf16)v;
}

// ---------------- small prep kernels ----------------
__global__ __launch_bounds__(256) void k_max(const float* __restrict__ pos, unsigned* __restrict__ outmax){
    __shared__ float s[256];
    int tid = threadIdx.x;
    float m = 0.0f;
    for (int i = blockIdx.x * 256 + tid; i < N_NODES; i += 256 * 256)
        m = fmaxf(m, pos[i]);
    s[tid] = m;
    __syncthreads();
    for (int off = 128; off > 0; off >>= 1){
        if (tid < off) s[tid] = fmaxf(s[tid], s[tid + off]);
        __syncthreads();
    }
    if (tid == 0) atomicMax(outmax, __float_as_uint(s[0]));
}

__global__ __launch_bounds__(256) void k_deg(const int* __restrict__ dst, int* __restrict__ deg){
    int i = blockIdx.x * 256 + threadIdx.x;
    if (i < N_EDGES) atomicAdd(deg + dst[i], 1);
}

__global__ __launch_bounds__(256) void k_prep(const float* __restrict__ pos, const unsigned* __restrict__ maxp,
                                              const int* __restrict__ deg,
                                              float* __restrict__ p, float* __restrict__ invdeg){
    int i = blockIdx.x * 256 + threadIdx.x;
    if (i < N_NODES){
        float mp = __uint_as_float(*maxp);
        p[i] = pos[i] / mp;
        invdeg[i] = 1.0f / fmaxf((float)deg[i], 1.0f);
    }
}

// ---------------- encoder (f32, runs once) ----------------
__device__ __forceinline__ void gemm44(const float* A, int lda, const float* __restrict__ W,
                                       int kq_begin, int kq_end, int r0, int c0, float acc[4][4]){
    for (int kq = kq_begin; kq < kq_end; ++kq){
        int k = kq * 4;
        float a[4][4], w[4][4];
        #pragma unroll
        for (int i = 0; i < 4; ++i){
            float4 v = *(const float4*)(A + (r0 + i) * lda + k);
            a[i][0] = v.x; a[i][1] = v.y; a[i][2] = v.z; a[i][3] = v.w;
        }
        #pragma unroll
        for (int kk = 0; kk < 4; ++kk){
            float4 v = *(const float4*)(W + (k + kk) * 128 + c0);
            w[kk][0] = v.x; w[kk][1] = v.y; w[kk][2] = v.z; w[kk][3] = v.w;
        }
        #pragma unroll
        for (int kk = 0; kk < 4; ++kk)
            #pragma unroll
            for (int i = 0; i < 4; ++i)
                #pragma unroll
                for (int j = 0; j < 4; ++j)
                    acc[i][j] = fmaf(a[i][kk], w[kk][j], acc[i][j]);
    }
}

__global__ __launch_bounds__(256) void k_enc(const float* __restrict__ x, const float* __restrict__ p,
                                             const float* __restrict__ vars,
                                             const float* __restrict__ W1, const float* __restrict__ b1,
                                             const float* __restrict__ W2, const float* __restrict__ b2,
                                             float* __restrict__ hA){
    __shared__ __align__(16) float sin_[32 * 32];
    __shared__ __align__(16) float sw1[32 * 128];
    __shared__ __align__(16) float sy[32 * 128];
    int tid = threadIdx.x;
    int n0 = blockIdx.x * 32;
    for (int i = tid; i < 32 * 32; i += 256){
        int e = i >> 5, k = i & 31;
        int node = n0 + e;
        float v;
        if (k < 25)       v = x[node * 25 + k];
        else if (k == 25) v = p[node];
        else if (k == 26) v = vars[node * 4 + 3] * (1.0f / T_MAX_F);
        else if (k < 30)  v = vars[node * 4 + (k - 27)];
        else              v = 0.0f;
        sin_[e * 32 + k] = v;
    }
    for (int i = tid; i < 32 * 128; i += 256){
        int r = i >> 7;
        sw1[i] = (r < 30) ? W1[i] : 0.0f;
    }
    __syncthreads();
    int c0 = (tid & 31) * 4, r0 = (tid >> 5) * 4;
    float acc[4][4] = {};
    gemm44(sin_, 32, sw1, 0, 8, r0, c0, acc);
    float4 bv = *(const float4*)(b1 + c0);
    float b_[4] = {bv.x, bv.y, bv.z, bv.w};
    #pragma unroll
    for (int i = 0; i < 4; ++i){
        float4 o;
        o.x = silu_f(acc[i][0] + b_[0]);
        o.y = silu_f(acc[i][1] + b_[1]);
        o.z = silu_f(acc[i][2] + b_[2]);
        o.w = silu_f(acc[i][3] + b_[3]);
        *(float4*)(sy + (r0 + i) * 128 + c0) = o;
    }
    __syncthreads();
    float acc2[4][4] = {};
    gemm44(sy, 128, W2, 0, 32, r0, c0, acc2);
    float4 b2v = *(const float4*)(b2 + c0);
    float bb[4] = {b2v.x, b2v.y, b2v.z, b2v.w};
    #pragma unroll
    for (int i = 0; i < 4; ++i){
        float4 o;
        o.x = silu_f(acc2[i][0] + bb[0]);
        o.y = silu_f(acc2[i][1] + bb[1]);
        o.z = silu_f(acc2[i][2] + bb[2]);
        o.w = silu_f(acc2[i][3] + bb[3]);
        *(float4*)(hA + (size_t)(n0 + r0 + i) * 128 + c0) = o;
    }
}

// ---------------- node precompute: LN(opt) + ra/rb GEMM ----------------
// A[node] = [h(128)|x(25)|p(1)|vars(4)|pad(2)] K=160; ra = A@Wra + b1; rb = A@Wrb.
__global__ __launch_bounds__(256) void k_npre(float* __restrict__ hA, const float* __restrict__ x,
                                              const float* __restrict__ p, const float* __restrict__ vars,
                                              const float* __restrict__ mu, const float* __restrict__ istd,
                                              int apply_ln,
                                              const __bf16* __restrict__ Wra, const __bf16* __restrict__ Wrb,
                                              const float* __restrict__ b1,
                                              __bf16* __restrict__ raO, __bf16* __restrict__ rbO){
    __shared__ __align__(16) __bf16 sA[10 * 64 * 8];     // 10 KB
    __shared__ __align__(16) float sOut[32 * 264];       // 33 KB (ra cols 0..127, rb 128..255)
    int tid = threadIdx.x;
    int n0 = blockIdx.x * 32;
    #pragma unroll
    for (int it = 0; it < 3; ++it){
        int j = tid + it * 256;
        if (j < 640){
            int f = j >> 6, lane = j & 63;
            int kb = f >> 1, mt = f & 1;
            int e = (lane & 15) + mt * 16, kh = lane >> 4;
            int node = n0 + e;
            bf16x8 o;
            if (kb < 4){
                int k0 = kb * 32 + kh * 8;
                float4 v0 = *(const float4*)(hA + (size_t)node * 128 + k0);
                float4 v1 = *(const float4*)(hA + (size_t)node * 128 + k0 + 4);
                if (apply_ln){
                    float4 m0 = *(const float4*)(mu + k0),   m1 = *(const float4*)(mu + k0 + 4);
                    float4 s0 = *(const float4*)(istd + k0), s1 = *(const float4*)(istd + k0 + 4);
                    v0.x = (v0.x - m0.x) * s0.x; v0.y = (v0.y - m0.y) * s0.y;
                    v0.z = (v0.z - m0.z) * s0.z; v0.w = (v0.w - m0.w) * s0.w;
                    v1.x = (v1.x - m1.x) * s1.x; v1.y = (v1.y - m1.y) * s1.y;
                    v1.z = (v1.z - m1.z) * s1.z; v1.w = (v1.w - m1.w) * s1.w;
                    *(float4*)(hA + (size_t)node * 128 + k0) = v0;
                    *(float4*)(hA + (size_t)node * 128 + k0 + 4) = v1;
                }
                o[0] = (__bf16)v0.x; o[1] = (__bf16)v0.y; o[2] = (__bf16)v0.z; o[3] = (__bf16)v0.w;
                o[4] = (__bf16)v1.x; o[5] = (__bf16)v1.y; o[6] = (__bf16)v1.z; o[7] = (__bf16)v1.w;
            } else {
                #pragma unroll
                for (int jj = 0; jj < 8; ++jj){
                    int fk = kh * 8 + jj;
                    float v;
                    if (fk < 25)       v = x[node * 25 + fk];
                    else if (fk == 25) v = p[node];
                    else if (fk < 30)  v = vars[node * 4 + (fk - 26)];
                    else               v = 0.0f;
                    o[jj] = (__bf16)v;
                }
            }
            *(bf16x8*)(sA + (f * 64 + lane) * 8) = o;
        }
    }
    __syncthreads();
    int w = tid >> 6, lane = tid & 63;
    int clo = lane & 15, rhi = lane >> 4;
    f32x4 z = {0.f, 0.f, 0.f, 0.f};
    f32x4 aR[2][2] = {{z, z}, {z, z}};
    f32x4 aB[2][2] = {{z, z}, {z, z}};
    #pragma unroll
    for (int kb = 0; kb < 5; ++kb){
        bf16x8 a0 = *(bf16x8*)(sA + ((kb * 2 + 0) * 64 + lane) * 8);
        bf16x8 a1 = *(bf16x8*)(sA + ((kb * 2 + 1) * 64 + lane) * 8);
        bf16x8 wr0 = *(const bf16x8*)(Wra + (size_t)((kb * 8 + 2 * w)     * 64 + lane) * 8);
        bf16x8 wr1 = *(const bf16x8*)(Wra + (size_t)((kb * 8 + 2 * w + 1) * 64 + lane) * 8);
        bf16x8 wb0 = *(const bf16x8*)(Wrb + (size_t)((kb * 8 + 2 * w)     * 64 + lane) * 8);
        bf16x8 wb1 = *(const bf16x8*)(Wrb + (size_t)((kb * 8 + 2 * w + 1) * 64 + lane) * 8);
        aR[0][0] = mfma16(a0, wr0, aR[0][0]);
        aR[0][1] = mfma16(a0, wr1, aR[0][1]);
        aR[1][0] = mfma16(a1, wr0, aR[1][0]);
        aR[1][1] = mfma16(a1, wr1, aR[1][1]);
        aB[0][0] = mfma16(a0, wb0, aB[0][0]);
        aB[0][1] = mfma16(a0, wb1, aB[0][1]);
        aB[1][0] = mfma16(a1, wb0, aB[1][0]);
        aB[1][1] = mfma16(a1, wb1, aB[1][1]);
    }
    #pragma unroll
    for (int nf = 0; nf < 2; ++nf){
        int col = (2 * w + nf) * 16 + clo;
        float bv = b1[col];
        #pragma unroll
        for (int mt = 0; mt < 2; ++mt)
            #pragma unroll
            for (int i = 0; i < 4; ++i){
                int e = mt * 16 + rhi * 4 + i;
                sOut[e * 264 + col]       = aR[mt][nf][i] + bv;
                sOut[e * 264 + 128 + col] = aB[mt][nf][i];
            }
    }
    __syncthreads();
    #pragma unroll
    for (int it = 0; it < 4; ++it){
        int j = tid + it * 256;             // 1024 items
        int row = j >> 5, c8 = j & 31;
        const float* src = sOut + row * 264 + c8 * 8;
        bf16x8 o;
        #pragma unroll
        for (int t = 0; t < 8; ++t) o[t] = (__bf16)src[t];
        __bf16* dstp = (c8 < 16) ? (raO + (size_t)(n0 + row) * 128 + c8 * 8)
                                 : (rbO + (size_t)(n0 + row) * 128 + (c8 - 16) * 8);
        *(bf16x8*)dstp = o;
    }
}

// ---------------- edge: y1 = silu(ra[dst]+rb[src]); m = silu(y1@W2+b2); atomic agg ----------------
__global__ __launch_bounds__(256) void k_edge2(const __bf16* __restrict__ ra, const __bf16* __restrict__ rb,
                                               const int* __restrict__ esrc, const int* __restrict__ edst,
                                               const __bf16* __restrict__ Wp2, const float* __restrict__ bias2,
                                               float* __restrict__ agg){
    __shared__ __align__(16) __bf16 sA[16 * 64 * 8];   // 16 KB (64 edges x 128 k, A-frag)
    __shared__ int sd[64], ss[64];
    int tid = threadIdx.x;
    int e0 = blockIdx.x * 64;
    if (tid < 64){ sd[tid] = edst[e0 + tid]; ss[tid] = esrc[e0 + tid]; }
    __syncthreads();
    #pragma unroll
    for (int it = 0; it < 4; ++it){
        int j = tid + it * 256;             // 1024 items: (frag f, lane)
        int f = j >> 6, lane = j & 63;
        int kb = f >> 2, mt = f & 3;
        int e = (lane & 15) + mt * 16;
        int k0 = kb * 32 + (lane >> 4) * 8;
        bf16x8 va = *(const bf16x8*)(ra + (size_t)sd[e] * 128 + k0);
        bf16x8 vb = *(const bf16x8*)(rb + (size_t)ss[e] * 128 + k0);
        bf16x8 o;
        #pragma unroll
        for (int t = 0; t < 8; ++t){
            float v = (float)va[t] + (float)vb[t];
            o[t] = (__bf16)silu_f(v);
        }
        *(bf16x8*)(sA + (f * 64 + lane) * 8) = o;
    }
    __syncthreads();
    int w = tid >> 6, lane = tid & 63;
    int cb0 = 2 * w, clo = lane & 15, rhi = lane >> 4;
    f32x4 z = {0.f, 0.f, 0.f, 0.f};
    f32x4 acc[4][2] = {{z, z}, {z, z}, {z, z}, {z, z}};
    #pragma unroll
    for (int kb = 0; kb < 4; ++kb){
        bf16x8 a0 = *(bf16x8*)(sA + ((kb * 4 + 0) * 64 + lane) * 8);
        bf16x8 a1 = *(bf16x8*)(sA + ((kb * 4 + 1) * 64 + lane) * 8);
        bf16x8 a2 = *(bf16x8*)(sA + ((kb * 4 + 2) * 64 + lane) * 8);
        bf16x8 a3 = *(bf16x8*)(sA + ((kb * 4 + 3) * 64 + lane) * 8);
        bf16x8 w0 = *(const bf16x8*)(Wp2 + (size_t)((kb * 8 + cb0)     * 64 + lane) * 8);
        bf16x8 w1 = *(const bf16x8*)(Wp2 + (size_t)((kb * 8 + cb0 + 1) * 64 + lane) * 8);
        acc[0][0] = mfma16(a0, w0, acc[0][0]);
        acc[0][1] = mfma16(a0, w1, acc[0][1]);
        acc[1][0] = mfma16(a1, w0, acc[1][0]);
        acc[1][1] = mfma16(a1, w1, acc[1][1]);
        acc[2][0] = mfma16(a2, w0, acc[2][0]);
        acc[2][1] = mfma16(a2, w1, acc[2][1]);
        acc[3][0] = mfma16(a3, w0, acc[3][0]);
        acc[3][1] = mfma16(a3, w1, acc[3][1]);
    }
    #pragma unroll
    for (int nf = 0; nf < 2; ++nf){
        int col = (cb0 + nf) * 16 + clo;
        float bv = bias2[col];
        #pragma unroll
        for (int mt = 0; mt < 4; ++mt)
            #pragma unroll
            for (int i = 0; i < 4; ++i){
                int e = mt * 16 + rhi * 4 + i;
                float v = silu_f(acc[mt][nf][i] + bv);
                atomicAdd(agg + (size_t)sd[e] * 128 + col, v);
            }
    }
}

// ---------------- node update MLP + fused batch stats ----------------
__global__ __launch_bounds__(256) void k_upd_m(float* __restrict__ hA, const float* __restrict__ agg,
                                               const float* __restrict__ vars, const float* __restrict__ invdeg,
                                               const __bf16* __restrict__ Wp1, const float* __restrict__ bias1,
                                               const __bf16* __restrict__ Wp2, const float* __restrict__ bias2,
                                               float* __restrict__ sacc, float* __restrict__ qacc){
    __shared__ __align__(16) __bf16 sA1[9 * 2 * 64 * 8];
    __shared__ __align__(16) __bf16 sA2[4 * 2 * 64 * 8];
    int tid = threadIdx.x;
    int n0 = blockIdx.x * 32;
    for (int i = tid; i < 32 * 64; i += 256){
        int e = i >> 6, rest = i & 63, which = rest >> 5, chunk = rest & 31;
        int node = n0 + e;
        float4 v;
        if (which == 0){
            v = *(const float4*)(hA + (size_t)node * 128 + chunk * 4);
        } else {
            v = *(const float4*)(agg + (size_t)node * 128 + chunk * 4);
            float s = invdeg[node];
            v.x *= s; v.y *= s; v.z *= s; v.w *= s;
        }
        int k = which * 128 + chunk * 4;
        bf16x4 o;
        o[0] = (__bf16)v.x; o[1] = (__bf16)v.y; o[2] = (__bf16)v.z; o[3] = (__bf16)v.w;
        *(bf16x4*)(sA1 + apos(e, k)) = o;
    }
    for (int i = tid; i < 32 * 32; i += 256){
        int e = i >> 5, kk = i & 31;
        float v = (kk < 4) ? vars[(size_t)(n0 + e) * 4 + kk] : 0.0f;
        sA1[apos(e, 256 + kk)] = (__bf16)v;
    }
    __syncthreads();
    int w = tid >> 6, lane = tid & 63;
    int cb0 = w * 2;
    int clo = lane & 15, rhi = lane >> 4;
    f32x4 z = {0.f, 0.f, 0.f, 0.f};
    f32x4 acc[2][2] = {{z, z}, {z, z}};
    #pragma unroll
    for (int kb = 0; kb < 9; ++kb){
        bf16x8 a0 = *(bf16x8*)(sA1 + ((kb * 2 + 0) * 64 + lane) * 8);
        bf16x8 a1 = *(bf16x8*)(sA1 + ((kb * 2 + 1) * 64 + lane) * 8);
        bf16x8 w0 = *(const bf16x8*)(Wp1 + (size_t)((kb * 8 + cb0) * 64 + lane) * 8);
        bf16x8 w1 = *(const bf16x8*)(Wp1 + (size_t)((kb * 8 + cb0 + 1) * 64 + lane) * 8);
        acc[0][0] = mfma16(a0, w0, acc[0][0]);
        acc[0][1] = mfma16(a0, w1, acc[0][1]);
        acc[1][0] = mfma16(a1, w0, acc[1][0]);
        acc[1][1] = mfma16(a1, w1, acc[1][1]);
    }
    #pragma unroll
    for (int nf = 0; nf < 2; ++nf){
        int col = (cb0 + nf) * 16 + clo;
        float bv = bias1[col];
        #pragma unroll
        for (int mt = 0; mt < 2; ++mt)
            #pragma unroll
            for (int i = 0; i < 4; ++i){
                int e = mt * 16 + rhi * 4 + i;
                float v = silu_f(acc[mt][nf][i] + bv);
                sA2[apos(e, col)] = (__bf16)v;
            }
    }
    __syncthreads();
    f32x4 acc2[2][2] = {{z, z}, {z, z}};
    #pragma unroll
    for (int kb = 0; kb < 4; ++kb){
        bf16x8 a0 = *(bf16x8*)(sA2 + ((kb * 2 + 0) * 64 + lane) * 8);
        bf16x8 a1 = *(bf16x8*)(sA2 + ((kb * 2 + 1) * 64 + lane) * 8);
        bf16x8 w0 = *(const bf16x8*)(Wp2 + (size_t)((kb * 8 + cb0) * 64 + lane) * 8);
        bf16x8 w1 = *(const bf16x8*)(Wp2 + (size_t)((kb * 8 + cb0 + 1) * 64 + lane) * 8);
        acc2[0][0] = mfma16(a0, w0, acc2[0][0]);
        acc2[0][1] = mfma16(a0, w1, acc2[0][1]);
        acc2[1][0] = mfma16(a1, w0, acc2[1][0]);
        acc2[1][1] = mfma16(a1, w1, acc2[1][1]);
    }
    float sm[2] = {0.f, 0.f}, sq[2] = {0.f, 0.f};
    #pragma unroll
    for (int nf = 0; nf < 2; ++nf){
        int col = (cb0 + nf) * 16 + clo;
        float bv = bias2[col];
        #pragma unroll
        for (int mt = 0; mt < 2; ++mt)
            #pragma unroll
            for (int i = 0; i < 4; ++i){
                int e = mt * 16 + rhi * 4 + i;
                size_t idx = (size_t)(n0 + e) * 128 + col;
                float u = silu_f(acc2[mt][nf][i] + bv);
                float hv = hA[idx] + u;
                hA[idx] = hv;
                sm[nf] += hv; sq[nf] += hv * hv;
            }
    }
    #pragma unroll
    for (int nf = 0; nf < 2; ++nf){
        float s = sm[nf], q = sq[nf];
        s += __shfl_xor(s, 16); q += __shfl_xor(q, 16);
        s += __shfl_xor(s, 32); q += __shfl_xor(q, 32);
        if (rhi == 0){
            int col = (cb0 + nf) * 16 + clo;
            atomicAdd(sacc + col, s);
            atomicAdd(qacc + col, q);
        }
    }
}

__global__ __launch_bounds__(128) void k_statfin(const float* __restrict__ sacc, const float* __restrict__ qacc,
                                                 float* __restrict__ mu, float* __restrict__ istd){
    int c = threadIdx.x;
    float m = sacc[c] * (1.0f / N_NODES);
    float v = qacc[c] * (1.0f / N_NODES) - m * m;
    mu[c] = m;
    istd[c] = rsqrtf(v + EPS_F);
}

// ---------------- decoder conv + output (LN applied inline) ----------------
__global__ __launch_bounds__(256) void k_dec(const float* __restrict__ h, const float* __restrict__ x,
                                             const float* __restrict__ dt,
                                             const float* __restrict__ W1, const float* __restrict__ b1,
                                             const float* __restrict__ W2, const float* __restrict__ b2,
                                             const float* __restrict__ mu, const float* __restrict__ istd,
                                             float* __restrict__ out){
    __shared__ __align__(16) float sh[8 * 128];
    __shared__ float so[8 * 308];
    __shared__ float sw1[128], sw2[112], sb1[8];
    int tid = threadIdx.x;
    int n0 = blockIdx.x * 8;
    for (int i = tid; i < 8 * 32; i += 256){
        int e = i >> 5, chunk = i & 31;
        float4 v = *(const float4*)(h + (size_t)(n0 + e) * 128 + chunk * 4);
        float4 m = *(const float4*)(mu + chunk * 4);
        float4 s = *(const float4*)(istd + chunk * 4);
        v.x = (v.x - m.x) * s.x; v.y = (v.y - m.y) * s.y;
        v.z = (v.z - m.z) * s.z; v.w = (v.w - m.w) * s.w;
        *(float4*)(sh + e * 128 + chunk * 4) = v;
    }
    if (tid < 128) sw1[tid] = W1[tid];
    else if (tid < 240) sw2[tid - 128] = W2[tid - 128];
    if (tid < 8) sb1[tid] = b1[tid];
    __syncthreads();
    int g = tid >> 5, lane = tid & 31;
    int node = n0 + g;
    for (int idx = lane; idx < 304; idx += 32){
        int c = idx / 38, j = idx % 38;
        float a = sb1[c];
        int base = 3 * j;
        #pragma unroll
        for (int k = 0; k < 16; ++k) a = fmaf(sh[g * 128 + base + k], sw1[c * 16 + k], a);
        so[g * 308 + c * 38 + j] = silu_f(a);
    }
    __syncthreads();
    if (lane < 25){
        float a = b2[0];
        #pragma unroll
        for (int c = 0; c < 8; ++c)
            #pragma unroll
            for (int k = 0; k < 14; ++k)
                a = fmaf(so[g * 308 + c * 38 + lane + k], sw2[c * 14 + k], a);
        float dtv = dt[0];
        out[(size_t)node * 25 + lane] = x[(size_t)node * 25 + 24] + dtv * (float)(lane + 1) * a;
    }
}

extern "C" void kernel_launch(void* const* d_in, const int* in_sizes, int n_in,
                              void* d_out, int out_size, void* d_ws, size_t ws_size,
                              hipStream_t stream){
    (void)in_sizes; (void)n_in; (void)out_size; (void)ws_size;
    const float* x      = (const float*)d_in[0];
    const float* pos    = (const float*)d_in[1];
    const float* vars   = (const float*)d_in[2];
    const float* dt     = (const float*)d_in[3];
    const int*   ei     = (const int*)d_in[4];
    const float* encW1  = (const float*)d_in[5];
    const float* encb1  = (const float*)d_in[6];
    const float* encW2  = (const float*)d_in[7];
    const float* encb2  = (const float*)d_in[8];
    const float* msgW1  = (const float*)d_in[9];
    const float* msgb1  = (const float*)d_in[10];
    const float* msgW2  = (const float*)d_in[11];
    const float* msgb2  = (const float*)d_in[12];
    const float* updW1  = (const float*)d_in[13];
    const float* updb1  = (const float*)d_in[14];
    const float* updW2  = (const float*)d_in[15];
    const float* updb2  = (const float*)d_in[16];
    const float* decW1  = (const float*)d_in[17];
    const float* decb1  = (const float*)d_in[18];
    const float* decW2  = (const float*)d_in[19];
    const float* decb2  = (const float*)d_in[20];
    float* out = (float*)d_out;

    float* ws = (float*)d_ws;
    size_t off = 0;
    float* hA      = ws + off; off += (size_t)N_NODES * 128;
    float* agg     = ws + off; off += (size_t)N_NODES * 128;
    float* sacc    = ws + off; off += 128;          // contiguous with agg for joint memset
    float* qacc    = ws + off; off += 128;
    float* p       = ws + off; off += N_NODES;
    float* invdeg  = ws + off; off += N_NODES;
    float* muArr   = ws + off; off += 6 * 128;
    float* istdArr = ws + off; off += 6 * 128;
    int* deg       = (int*)(ws + off); off += N_NODES;
    unsigned* maxp = (unsigned*)(ws + off); off += 2;
    __bf16* wpack  = (__bf16*)(ws + off); off += (PK_TOTAL + 1) / 2;
    __bf16* raB    = (__bf16*)(ws + off); off += (size_t)N_NODES * 64;
    __bf16* rbB    = (__bf16*)(ws + off); off += (size_t)N_NODES * 64;

    __bf16* pra = wpack;
    __bf16* prb = pra + PK_RA;
    __bf16* pm2 = prb + PK_RB;
    __bf16* pu1 = pm2 + PK_M2;
    __bf16* pu2 = pu1 + PK_U1;

    const int* esrc = ei;
    const int* edst = ei + N_EDGES;

    hipMemsetAsync(deg, 0, (size_t)N_NODES * sizeof(int) + sizeof(unsigned), stream);

    k_pack<<<(PK_TOTAL + 255) / 256, 256, 0, stream>>>(msgW1, msgW2, updW1, updW2, wpack);
    k_max<<<256, 256, 0, stream>>>(pos, maxp);
    k_deg<<<N_EDGES / 256, 256, 0, stream>>>(edst, deg);
    k_prep<<<N_NODES / 256, 256, 0, stream>>>(pos, maxp, deg, p, invdeg);
    k_enc<<<N_NODES / 32, 256, 0, stream>>>(x, p, vars, encW1, encb1, encW2, encb2, hA);

    for (int l = 0; l < N_LAYERS; ++l){
        hipMemsetAsync(agg, 0, ((size_t)N_NODES * 128 + 256) * sizeof(float), stream);
        const float* muPrev   = (l > 0) ? (muArr + (size_t)(l - 1) * 128) : muArr;
        const float* istdPrev = (l > 0) ? (istdArr + (size_t)(l - 1) * 128) : istdArr;
        k_npre<<<N_NODES / 32, 256, 0, stream>>>(hA, x, p, vars, muPrev, istdPrev, (l > 0) ? 1 : 0,
            pra + (size_t)l * 20480, prb + (size_t)l * 20480, msgb1 + l * 128, raB, rbB);
        k_edge2<<<N_EDGES / 64, 256, 0, stream>>>(raB, rbB, esrc, edst,
            pm2 + (size_t)l * 16384, msgb2 + l * 128, agg);
        k_upd_m<<<N_NODES / 32, 256, 0, stream>>>(hA, agg, vars, invdeg,
            pu1 + (size_t)l * 36864, updb1 + l * 128,
            pu2 + (size_t)l * 16384, updb2 + l * 128, sacc, qacc);
        k_statfin<<<1, 128, 0, stream>>>(sacc, qacc, muArr + (size_t)l * 128, istdArr + (size_t)l * 128);
    }

    k_dec<<<N_NODES / 8, 256, 0, stream>>>(hA, x, dt, decW1, decb1, decW2, decb2,
                                           muArr + 5 * 128, istdArr + 5 * 128, out);
}

// Round 4
// 1103.850 us; speedup vs baseline: 1.3504x; 1.3504x over previous
//
#include <hip/hip_runtime.h>
#include <math.h>

#define N_NODES 65536
#define N_EDGES 262144
#define N_LAYERS 6
#define T_MAX_F 16.0f
#define EPS_F 1e-5f

typedef float  f32x4  __attribute__((ext_vector_type(4)));
typedef __bf16 bf16x8 __attribute__((ext_vector_type(8)));
typedef __bf16 bf16x4 __attribute__((ext_vector_type(4)));

__device__ __forceinline__ float silu_f(float v){
    return v / (1.0f + __expf(-v));
}

__device__ __forceinline__ f32x4 mfma16(bf16x8 a, bf16x8 b, f32x4 c){
    return __builtin_amdgcn_mfma_f32_16x16x32_bf16(a, b, c, 0, 0, 0);
}

// A-fragment LDS halfword index, M=32 tiles (2 row-tiles):
__device__ __forceinline__ int apos(int row, int k){
    return (((k >> 5) * 2 + (row >> 4)) * 64 + ((row & 15) | (((k >> 3) & 3) << 4))) * 8 + (k & 7);
}

// ---------------- weight prepack ----------------
// B-fragment packed layout per weight: [kb][cb][lane(64)][elem(8)],
// col = cb*16 + (lane&15), k = kb*32 + (lane>>4)*8 + elem.
#define PK_RA (6 * 20480)   // msg W1 dst-side, K=160 (5 kb)
#define PK_RB (6 * 20480)   // msg W1 src-side
#define PK_M2 (6 * 16384)   // msg W2, K=128
#define PK_U1 (6 * 36864)   // upd W1, K=288 pad
#define PK_U2 (6 * 16384)   // upd W2, K=128
#define PK_TOTAL (PK_RA + PK_RB + PK_M2 + PK_U1 + PK_U2)

__global__ __launch_bounds__(256) void k_pack(const float* __restrict__ msgW1, const float* __restrict__ msgW2,
                                              const float* __restrict__ updW1, const float* __restrict__ updW2,
                                              __bf16* __restrict__ out){
    int pg = blockIdx.x * 256 + threadIdx.x;
    if (pg >= PK_TOTAL) return;
    int p = pg;
    int mode; const float* W; int perL;
    if (p < PK_RA){ mode = 0; W = msgW1; perL = 20480; }
    else if ((p -= PK_RA) < PK_RB){ mode = 1; W = msgW1; perL = 20480; }
    else if ((p -= PK_RB) < PK_M2){ mode = 2; W = msgW2; perL = 16384; }
    else if ((p -= PK_M2) < PK_U1){ mode = 3; W = updW1; perL = 36864; }
    else { p -= PK_U1; mode = 4; W = updW2; perL = 16384; }
    int l = p / perL, q = p % perL;
    int elem = q & 7, lane = (q >> 3) & 63, cb = (q >> 9) & 7, kb = q >> 12;
    int col = cb * 16 + (lane & 15);
    int k = kb * 32 + ((lane >> 4) << 3) + elem;
    float v = 0.0f;
    if (mode == 0){
        int r = -1;
        if (k < 128) r = k;
        else if (k < 153) r = 256 + (k - 128);
        else if (k == 153) r = 281;
        else if (k < 158) r = 282 + (k - 154);
        if (r >= 0) v = W[(size_t)l * 286 * 128 + (size_t)r * 128 + col];
    } else if (mode == 1){
        if (k < 128) v = W[(size_t)l * 286 * 128 + (size_t)(128 + k) * 128 + col];
        else if (k < 153) v = -W[(size_t)l * 286 * 128 + (size_t)(256 + (k - 128)) * 128 + col];
        else if (k == 153) v = -W[(size_t)l * 286 * 128 + (size_t)281 * 128 + col];
    } else {
        int Kreal = (mode == 3) ? 260 : 128;
        if (k < Kreal) v = W[(size_t)l * Kreal * 128 + (size_t)k * 128 + col];
    }
    out[pg] = (__bf16)v;
}

// ---------------- small prep kernels ----------------
__global__ __launch_bounds__(256) void k_max(const float* __restrict__ pos, unsigned* __restrict__ outmax){
    __shared__ float s[256];
    int tid = threadIdx.x;
    float m = 0.0f;
    for (int i = blockIdx.x * 256 + tid; i < N_NODES; i += 256 * 256)
        m = fmaxf(m, pos[i]);
    s[tid] = m;
    __syncthreads();
    for (int off = 128; off > 0; off >>= 1){
        if (tid < off) s[tid] = fmaxf(s[tid], s[tid + off]);
        __syncthreads();
    }
    if (tid == 0) atomicMax(outmax, __float_as_uint(s[0]));
}

__global__ __launch_bounds__(256) void k_deg(const int* __restrict__ dst, int* __restrict__ deg){
    int i = blockIdx.x * 256 + threadIdx.x;
    if (i < N_EDGES) atomicAdd(deg + dst[i], 1);
}

__global__ __launch_bounds__(256) void k_prep(const float* __restrict__ pos, const unsigned* __restrict__ maxp,
                                              const int* __restrict__ deg,
                                              float* __restrict__ p, float* __restrict__ invdeg){
    int i = blockIdx.x * 256 + threadIdx.x;
    if (i < N_NODES){
        float mp = __uint_as_float(*maxp);
        p[i] = pos[i] / mp;
        invdeg[i] = 1.0f / fmaxf((float)deg[i], 1.0f);
    }
}

// ---------------- CSR build: scan + scatter ----------------
__global__ __launch_bounds__(256) void k_scan1(const int* __restrict__ deg, int* __restrict__ csum){
    __shared__ int s[256];
    int c = blockIdx.x, t = threadIdx.x;
    s[t] = deg[c * 256 + t];
    __syncthreads();
    for (int o = 128; o > 0; o >>= 1){ if (t < o) s[t] += s[t + o]; __syncthreads(); }
    if (t == 0) csum[c] = s[0];
}

__global__ __launch_bounds__(256) void k_scan2(const int* __restrict__ csum, int* __restrict__ coff){
    __shared__ int s[256];
    int t = threadIdx.x;
    s[t] = csum[t];
    __syncthreads();
    for (int o = 1; o < 256; o <<= 1){
        int v = (t >= o) ? s[t - o] : 0;
        __syncthreads();
        s[t] += v;
        __syncthreads();
    }
    coff[t] = s[t] - csum[t];   // exclusive
}

__global__ __launch_bounds__(256) void k_scan3(const int* __restrict__ deg, const int* __restrict__ coff,
                                               int* __restrict__ cursor){
    __shared__ int s[256];
    int c = blockIdx.x, t = threadIdx.x;
    int d = deg[c * 256 + t];
    s[t] = d;
    __syncthreads();
    for (int o = 1; o < 256; o <<= 1){
        int v = (t >= o) ? s[t - o] : 0;
        __syncthreads();
        s[t] += v;
        __syncthreads();
    }
    cursor[c * 256 + t] = coff[c] + s[t] - d;
}

__global__ __launch_bounds__(256) void k_scatter(const int* __restrict__ esrc, const int* __restrict__ edst,
                                                 int* __restrict__ cursor,
                                                 int* __restrict__ ssrcS, int* __restrict__ sdstS){
    int e = blockIdx.x * 256 + threadIdx.x;
    if (e < N_EDGES){
        int d = edst[e];
        int slot = atomicAdd(cursor + d, 1);
        ssrcS[slot] = esrc[e];
        sdstS[slot] = d;
    }
}

// ---------------- encoder (f32, runs once) ----------------
__device__ __forceinline__ void gemm44(const float* A, int lda, const float* __restrict__ W,
                                       int kq_begin, int kq_end, int r0, int c0, float acc[4][4]){
    for (int kq = kq_begin; kq < kq_end; ++kq){
        int k = kq * 4;
        float a[4][4], w[4][4];
        #pragma unroll
        for (int i = 0; i < 4; ++i){
            float4 v = *(const float4*)(A + (r0 + i) * lda + k);
            a[i][0] = v.x; a[i][1] = v.y; a[i][2] = v.z; a[i][3] = v.w;
        }
        #pragma unroll
        for (int kk = 0; kk < 4; ++kk){
            float4 v = *(const float4*)(W + (k + kk) * 128 + c0);
            w[kk][0] = v.x; w[kk][1] = v.y; w[kk][2] = v.z; w[kk][3] = v.w;
        }
        #pragma unroll
        for (int kk = 0; kk < 4; ++kk)
            #pragma unroll
            for (int i = 0; i < 4; ++i)
                #pragma unroll
                for (int j = 0; j < 4; ++j)
                    acc[i][j] = fmaf(a[i][kk], w[kk][j], acc[i][j]);
    }
}

__global__ __launch_bounds__(256) void k_enc(const float* __restrict__ x, const float* __restrict__ p,
                                             const float* __restrict__ vars,
                                             const float* __restrict__ W1, const float* __restrict__ b1,
                                             const float* __restrict__ W2, const float* __restrict__ b2,
                                             float* __restrict__ hA){
    __shared__ __align__(16) float sin_[32 * 32];
    __shared__ __align__(16) float sw1[32 * 128];
    __shared__ __align__(16) float sy[32 * 128];
    int tid = threadIdx.x;
    int n0 = blockIdx.x * 32;
    for (int i = tid; i < 32 * 32; i += 256){
        int e = i >> 5, k = i & 31;
        int node = n0 + e;
        float v;
        if (k < 25)       v = x[node * 25 + k];
        else if (k == 25) v = p[node];
        else if (k == 26) v = vars[node * 4 + 3] * (1.0f / T_MAX_F);
        else if (k < 30)  v = vars[node * 4 + (k - 27)];
        else              v = 0.0f;
        sin_[e * 32 + k] = v;
    }
    for (int i = tid; i < 32 * 128; i += 256){
        int r = i >> 7;
        sw1[i] = (r < 30) ? W1[i] : 0.0f;
    }
    __syncthreads();
    int c0 = (tid & 31) * 4, r0 = (tid >> 5) * 4;
    float acc[4][4] = {};
    gemm44(sin_, 32, sw1, 0, 8, r0, c0, acc);
    float4 bv = *(const float4*)(b1 + c0);
    float b_[4] = {bv.x, bv.y, bv.z, bv.w};
    #pragma unroll
    for (int i = 0; i < 4; ++i){
        float4 o;
        o.x = silu_f(acc[i][0] + b_[0]);
        o.y = silu_f(acc[i][1] + b_[1]);
        o.z = silu_f(acc[i][2] + b_[2]);
        o.w = silu_f(acc[i][3] + b_[3]);
        *(float4*)(sy + (r0 + i) * 128 + c0) = o;
    }
    __syncthreads();
    float acc2[4][4] = {};
    gemm44(sy, 128, W2, 0, 32, r0, c0, acc2);
    float4 b2v = *(const float4*)(b2 + c0);
    float bb[4] = {b2v.x, b2v.y, b2v.z, b2v.w};
    #pragma unroll
    for (int i = 0; i < 4; ++i){
        float4 o;
        o.x = silu_f(acc2[i][0] + bb[0]);
        o.y = silu_f(acc2[i][1] + bb[1]);
        o.z = silu_f(acc2[i][2] + bb[2]);
        o.w = silu_f(acc2[i][3] + bb[3]);
        *(float4*)(hA + (size_t)(n0 + r0 + i) * 128 + c0) = o;
    }
}

// ---------------- node precompute: on-the-fly LN + ra/rb GEMM ----------------
// A[node] = [LN(h)(128)|x(25)|p(1)|vars(4)|pad(2)] K=160; ra = A@Wra + b1 (f32); rb = A@Wrb (bf16).
__global__ __launch_bounds__(256) void k_npre(const float* __restrict__ hA, const float* __restrict__ x,
                                              const float* __restrict__ p, const float* __restrict__ vars,
                                              const float* __restrict__ mu, const float* __restrict__ istd,
                                              int apply_ln,
                                              const __bf16* __restrict__ Wra, const __bf16* __restrict__ Wrb,
                                              const float* __restrict__ b1,
                                              float* __restrict__ raO, __bf16* __restrict__ rbO){
    __shared__ __align__(16) __bf16 sA[10 * 64 * 8];     // 10 KB
    __shared__ __align__(16) float sOut[32 * 264];       // 33 KB (ra cols 0..127, rb 128..255)
    int tid = threadIdx.x;
    int n0 = blockIdx.x * 32;
    #pragma unroll
    for (int it = 0; it < 3; ++it){
        int j = tid + it * 256;
        if (j < 640){
            int f = j >> 6, lane = j & 63;
            int kb = f >> 1, mt = f & 1;
            int e = (lane & 15) + mt * 16, kh = lane >> 4;
            int node = n0 + e;
            bf16x8 o;
            if (kb < 4){
                int k0 = kb * 32 + kh * 8;
                float4 v0 = *(const float4*)(hA + (size_t)node * 128 + k0);
                float4 v1 = *(const float4*)(hA + (size_t)node * 128 + k0 + 4);
                if (apply_ln){
                    float4 m0 = *(const float4*)(mu + k0),   m1 = *(const float4*)(mu + k0 + 4);
                    float4 s0 = *(const float4*)(istd + k0), s1 = *(const float4*)(istd + k0 + 4);
                    v0.x = (v0.x - m0.x) * s0.x; v0.y = (v0.y - m0.y) * s0.y;
                    v0.z = (v0.z - m0.z) * s0.z; v0.w = (v0.w - m0.w) * s0.w;
                    v1.x = (v1.x - m1.x) * s1.x; v1.y = (v1.y - m1.y) * s1.y;
                    v1.z = (v1.z - m1.z) * s1.z; v1.w = (v1.w - m1.w) * s1.w;
                }
                o[0] = (__bf16)v0.x; o[1] = (__bf16)v0.y; o[2] = (__bf16)v0.z; o[3] = (__bf16)v0.w;
                o[4] = (__bf16)v1.x; o[5] = (__bf16)v1.y; o[6] = (__bf16)v1.z; o[7] = (__bf16)v1.w;
            } else {
                #pragma unroll
                for (int jj = 0; jj < 8; ++jj){
                    int fk = kh * 8 + jj;
                    float v;
                    if (fk < 25)       v = x[node * 25 + fk];
                    else if (fk == 25) v = p[node];
                    else if (fk < 30)  v = vars[node * 4 + (fk - 26)];
                    else               v = 0.0f;
                    o[jj] = (__bf16)v;
                }
            }
            *(bf16x8*)(sA + (f * 64 + lane) * 8) = o;
        }
    }
    __syncthreads();
    int w = tid >> 6, lane = tid & 63;
    int clo = lane & 15, rhi = lane >> 4;
    f32x4 z = {0.f, 0.f, 0.f, 0.f};
    f32x4 aR[2][2] = {{z, z}, {z, z}};
    f32x4 aB[2][2] = {{z, z}, {z, z}};
    #pragma unroll
    for (int kb = 0; kb < 5; ++kb){
        bf16x8 a0 = *(bf16x8*)(sA + ((kb * 2 + 0) * 64 + lane) * 8);
        bf16x8 a1 = *(bf16x8*)(sA + ((kb * 2 + 1) * 64 + lane) * 8);
        bf16x8 wr0 = *(const bf16x8*)(Wra + (size_t)((kb * 8 + 2 * w)     * 64 + lane) * 8);
        bf16x8 wr1 = *(const bf16x8*)(Wra + (size_t)((kb * 8 + 2 * w + 1) * 64 + lane) * 8);
        bf16x8 wb0 = *(const bf16x8*)(Wrb + (size_t)((kb * 8 + 2 * w)     * 64 + lane) * 8);
        bf16x8 wb1 = *(const bf16x8*)(Wrb + (size_t)((kb * 8 + 2 * w + 1) * 64 + lane) * 8);
        aR[0][0] = mfma16(a0, wr0, aR[0][0]);
        aR[0][1] = mfma16(a0, wr1, aR[0][1]);
        aR[1][0] = mfma16(a1, wr0, aR[1][0]);
        aR[1][1] = mfma16(a1, wr1, aR[1][1]);
        aB[0][0] = mfma16(a0, wb0, aB[0][0]);
        aB[0][1] = mfma16(a0, wb1, aB[0][1]);
        aB[1][0] = mfma16(a1, wb0, aB[1][0]);
        aB[1][1] = mfma16(a1, wb1, aB[1][1]);
    }
    #pragma unroll
    for (int nf = 0; nf < 2; ++nf){
        int col = (2 * w + nf) * 16 + clo;
        float bv = b1[col];
        #pragma unroll
        for (int mt = 0; mt < 2; ++mt)
            #pragma unroll
            for (int i = 0; i < 4; ++i){
                int e = mt * 16 + rhi * 4 + i;
                sOut[e * 264 + col]       = aR[mt][nf][i] + bv;
                sOut[e * 264 + 128 + col] = aB[mt][nf][i];
            }
    }
    __syncthreads();
    #pragma unroll
    for (int it = 0; it < 4; ++it){
        int j = tid + it * 256;             // 1024 items
        int row = j >> 5, c8 = j & 31;
        const float* src = sOut + row * 264 + c8 * 8;
        if (c8 < 16){
            float4 v0 = *(const float4*)(src);
            float4 v1 = *(const float4*)(src + 4);
            float* dstp = raO + (size_t)(n0 + row) * 128 + c8 * 8;
            *(float4*)(dstp)     = v0;
            *(float4*)(dstp + 4) = v1;
        } else {
            bf16x8 o;
            #pragma unroll
            for (int t = 0; t < 8; ++t) o[t] = (__bf16)src[t];
            *(bf16x8*)(rbO + (size_t)(n0 + row) * 128 + (c8 - 16) * 8) = o;
        }
    }
}

// ---------------- edge (CSR-sorted): y1 = silu(ra[dst]+rb[src]); m = silu(y1@W2+b2);
// segmented LDS reduction by dst, then one atomicAdd per (segment, col). ----------------
__global__ __launch_bounds__(256) void k_edge3(const float* __restrict__ ra, const __bf16* __restrict__ rb,
                                               const int* __restrict__ ssrcS, const int* __restrict__ sdstS,
                                               const __bf16* __restrict__ Wp2, const float* __restrict__ bias2,
                                               float* __restrict__ agg){
    __shared__ __align__(16) unsigned char smem[64 * 128 * 4];   // 32 KB: sA (phase1/2) then msum (phase3/4)
    __shared__ int sd[64], ss[64];
    __bf16* sA   = (__bf16*)smem;
    float*  msum = (float*)smem;
    int tid = threadIdx.x;
    int e0 = blockIdx.x * 64;
    if (tid < 64){ sd[tid] = sdstS[e0 + tid]; ss[tid] = ssrcS[e0 + tid]; }
    __syncthreads();
    // phase 1: y1 staging into A-frags
    #pragma unroll
    for (int it = 0; it < 4; ++it){
        int j = tid + it * 256;             // 1024 items
        int f = j >> 6, lane = j & 63;
        int kb = f >> 2, mt = f & 3;
        int e = (lane & 15) + mt * 16;
        int k0 = kb * 32 + (lane >> 4) * 8;
        const float* rap = ra + (size_t)sd[e] * 128 + k0;
        float4 v0 = *(const float4*)(rap);
        float4 v1 = *(const float4*)(rap + 4);
        bf16x8 vb = *(const bf16x8*)(rb + (size_t)ss[e] * 128 + k0);
        bf16x8 o;
        o[0] = (__bf16)silu_f(v0.x + (float)vb[0]);
        o[1] = (__bf16)silu_f(v0.y + (float)vb[1]);
        o[2] = (__bf16)silu_f(v0.z + (float)vb[2]);
        o[3] = (__bf16)silu_f(v0.w + (float)vb[3]);
        o[4] = (__bf16)silu_f(v1.x + (float)vb[4]);
        o[5] = (__bf16)silu_f(v1.y + (float)vb[5]);
        o[6] = (__bf16)silu_f(v1.z + (float)vb[6]);
        o[7] = (__bf16)silu_f(v1.w + (float)vb[7]);
        *(bf16x8*)(sA + (f * 64 + lane) * 8) = o;
    }
    __syncthreads();
    // phase 2: GEMM2 (64x128 @ 128x128)
    int w = tid >> 6, lane = tid & 63;
    int cb0 = 2 * w, clo = lane & 15, rhi = lane >> 4;
    f32x4 z = {0.f, 0.f, 0.f, 0.f};
    f32x4 acc[4][2] = {{z, z}, {z, z}, {z, z}, {z, z}};
    #pragma unroll
    for (int kb = 0; kb < 4; ++kb){
        bf16x8 a0 = *(bf16x8*)(sA + ((kb * 4 + 0) * 64 + lane) * 8);
        bf16x8 a1 = *(bf16x8*)(sA + ((kb * 4 + 1) * 64 + lane) * 8);
        bf16x8 a2 = *(bf16x8*)(sA + ((kb * 4 + 2) * 64 + lane) * 8);
        bf16x8 a3 = *(bf16x8*)(sA + ((kb * 4 + 3) * 64 + lane) * 8);
        bf16x8 w0 = *(const bf16x8*)(Wp2 + (size_t)((kb * 8 + cb0)     * 64 + lane) * 8);
        bf16x8 w1 = *(const bf16x8*)(Wp2 + (size_t)((kb * 8 + cb0 + 1) * 64 + lane) * 8);
        acc[0][0] = mfma16(a0, w0, acc[0][0]);
        acc[0][1] = mfma16(a0, w1, acc[0][1]);
        acc[1][0] = mfma16(a1, w0, acc[1][0]);
        acc[1][1] = mfma16(a1, w1, acc[1][1]);
        acc[2][0] = mfma16(a2, w0, acc[2][0]);
        acc[2][1] = mfma16(a2, w1, acc[2][1]);
        acc[3][0] = mfma16(a3, w0, acc[3][0]);
        acc[3][1] = mfma16(a3, w1, acc[3][1]);
    }
    __syncthreads();   // all sA reads complete before msum overlay
    // phase 3: m = silu(acc + b2) -> msum[row][col]
    #pragma unroll
    for (int nf = 0; nf < 2; ++nf){
        int col = (cb0 + nf) * 16 + clo;
        float bv = bias2[col];
        #pragma unroll
        for (int mt = 0; mt < 4; ++mt)
            #pragma unroll
            for (int i = 0; i < 4; ++i){
                int row = mt * 16 + rhi * 4 + i;
                msum[row * 128 + col] = silu_f(acc[mt][nf][i] + bv);
            }
    }
    __syncthreads();
    // phase 4: segmented reduction over sorted dst runs
    int col = tid & 127, half = tid >> 7;
    int base = half * 32;
    float run = 0.0f;
    for (int r = 0; r < 32; ++r){
        int row = base + r;
        run += msum[row * 128 + col];
        bool flush = (r == 31) || (sd[row + 1] != sd[row]);
        if (flush){
            atomicAdd(agg + (size_t)sd[row] * 128 + col, run);
            run = 0.0f;
        }
    }
}

// ---------------- node update MLP (on-the-fly LN) + fused batch stats ----------------
__global__ __launch_bounds__(256) void k_upd_m(float* __restrict__ hA, const float* __restrict__ agg,
                                               const float* __restrict__ vars, const float* __restrict__ invdeg,
                                               const float* __restrict__ mu, const float* __restrict__ istd,
                                               int apply_ln,
                                               const __bf16* __restrict__ Wp1, const float* __restrict__ bias1,
                                               const __bf16* __restrict__ Wp2, const float* __restrict__ bias2,
                                               float* __restrict__ sacc, float* __restrict__ qacc){
    __shared__ __align__(16) __bf16 sA1[9 * 2 * 64 * 8];
    __shared__ __align__(16) __bf16 sA2[4 * 2 * 64 * 8];
    int tid = threadIdx.x;
    int n0 = blockIdx.x * 32;
    for (int i = tid; i < 32 * 64; i += 256){
        int e = i >> 6, rest = i & 63, which = rest >> 5, chunk = rest & 31;
        int node = n0 + e;
        float4 v;
        if (which == 0){
            v = *(const float4*)(hA + (size_t)node * 128 + chunk * 4);
            if (apply_ln){
                float4 m = *(const float4*)(mu + chunk * 4);
                float4 s = *(const float4*)(istd + chunk * 4);
                v.x = (v.x - m.x) * s.x; v.y = (v.y - m.y) * s.y;
                v.z = (v.z - m.z) * s.z; v.w = (v.w - m.w) * s.w;
            }
        } else {
            v = *(const float4*)(agg + (size_t)node * 128 + chunk * 4);
            float s = invdeg[node];
            v.x *= s; v.y *= s; v.z *= s; v.w *= s;
        }
        int k = which * 128 + chunk * 4;
        bf16x4 o;
        o[0] = (__bf16)v.x; o[1] = (__bf16)v.y; o[2] = (__bf16)v.z; o[3] = (__bf16)v.w;
        *(bf16x4*)(sA1 + apos(e, k)) = o;
    }
    for (int i = tid; i < 32 * 32; i += 256){
        int e = i >> 5, kk = i & 31;
        float v = (kk < 4) ? vars[(size_t)(n0 + e) * 4 + kk] : 0.0f;
        sA1[apos(e, 256 + kk)] = (__bf16)v;
    }
    __syncthreads();
    int w = tid >> 6, lane = tid & 63;
    int cb0 = w * 2;
    int clo = lane & 15, rhi = lane >> 4;
    f32x4 z = {0.f, 0.f, 0.f, 0.f};
    f32x4 acc[2][2] = {{z, z}, {z, z}};
    #pragma unroll
    for (int kb = 0; kb < 9; ++kb){
        bf16x8 a0 = *(bf16x8*)(sA1 + ((kb * 2 + 0) * 64 + lane) * 8);
        bf16x8 a1 = *(bf16x8*)(sA1 + ((kb * 2 + 1) * 64 + lane) * 8);
        bf16x8 w0 = *(const bf16x8*)(Wp1 + (size_t)((kb * 8 + cb0) * 64 + lane) * 8);
        bf16x8 w1 = *(const bf16x8*)(Wp1 + (size_t)((kb * 8 + cb0 + 1) * 64 + lane) * 8);
        acc[0][0] = mfma16(a0, w0, acc[0][0]);
        acc[0][1] = mfma16(a0, w1, acc[0][1]);
        acc[1][0] = mfma16(a1, w0, acc[1][0]);
        acc[1][1] = mfma16(a1, w1, acc[1][1]);
    }
    #pragma unroll
    for (int nf = 0; nf < 2; ++nf){
        int col = (cb0 + nf) * 16 + clo;
        float bv = bias1[col];
        #pragma unroll
        for (int mt = 0; mt < 2; ++mt)
            #pragma unroll
            for (int i = 0; i < 4; ++i){
                int e = mt * 16 + rhi * 4 + i;
                float v = silu_f(acc[mt][nf][i] + bv);
                sA2[apos(e, col)] = (__bf16)v;
            }
    }
    __syncthreads();
    f32x4 acc2[2][2] = {{z, z}, {z, z}};
    #pragma unroll
    for (int kb = 0; kb < 4; ++kb){
        bf16x8 a0 = *(bf16x8*)(sA2 + ((kb * 2 + 0) * 64 + lane) * 8);
        bf16x8 a1 = *(bf16x8*)(sA2 + ((kb * 2 + 1) * 64 + lane) * 8);
        bf16x8 w0 = *(const bf16x8*)(Wp2 + (size_t)((kb * 8 + cb0) * 64 + lane) * 8);
        bf16x8 w1 = *(const bf16x8*)(Wp2 + (size_t)((kb * 8 + cb0 + 1) * 64 + lane) * 8);
        acc2[0][0] = mfma16(a0, w0, acc2[0][0]);
        acc2[0][1] = mfma16(a0, w1, acc2[0][1]);
        acc2[1][0] = mfma16(a1, w0, acc2[1][0]);
        acc2[1][1] = mfma16(a1, w1, acc2[1][1]);
    }
    float sm[2] = {0.f, 0.f}, sq[2] = {0.f, 0.f};
    #pragma unroll
    for (int nf = 0; nf < 2; ++nf){
        int col = (cb0 + nf) * 16 + clo;
        float bv = bias2[col];
        float muv = apply_ln ? mu[col] : 0.0f;
        float sdv = apply_ln ? istd[col] : 1.0f;
        #pragma unroll
        for (int mt = 0; mt < 2; ++mt)
            #pragma unroll
            for (int i = 0; i < 4; ++i){
                int e = mt * 16 + rhi * 4 + i;
                size_t idx = (size_t)(n0 + e) * 128 + col;
                float u = silu_f(acc2[mt][nf][i] + bv);
                float hln = (hA[idx] - muv) * sdv;
                float hv = hln + u;
                hA[idx] = hv;
                sm[nf] += hv; sq[nf] += hv * hv;
            }
    }
    #pragma unroll
    for (int nf = 0; nf < 2; ++nf){
        float s = sm[nf], q = sq[nf];
        s += __shfl_xor(s, 16); q += __shfl_xor(q, 16);
        s += __shfl_xor(s, 32); q += __shfl_xor(q, 32);
        if (rhi == 0){
            int col = (cb0 + nf) * 16 + clo;
            atomicAdd(sacc + col, s);
            atomicAdd(qacc + col, q);
        }
    }
}

__global__ __launch_bounds__(128) void k_statfin(const float* __restrict__ sacc, const float* __restrict__ qacc,
                                                 float* __restrict__ mu, float* __restrict__ istd){
    int c = threadIdx.x;
    float m = sacc[c] * (1.0f / N_NODES);
    float v = qacc[c] * (1.0f / N_NODES) - m * m;
    mu[c] = m;
    istd[c] = rsqrtf(v + EPS_F);
}

// ---------------- decoder conv + output (LN applied inline) ----------------
__global__ __launch_bounds__(256) void k_dec(const float* __restrict__ h, const float* __restrict__ x,
                                             const float* __restrict__ dt,
                                             const float* __restrict__ W1, const float* __restrict__ b1,
                                             const float* __restrict__ W2, const float* __restrict__ b2,
                                             const float* __restrict__ mu, const float* __restrict__ istd,
                                             float* __restrict__ out){
    __shared__ __align__(16) float sh[8 * 128];
    __shared__ float so[8 * 308];
    __shared__ float sw1[128], sw2[112], sb1[8];
    int tid = threadIdx.x;
    int n0 = blockIdx.x * 8;
    for (int i = tid; i < 8 * 32; i += 256){
        int e = i >> 5, chunk = i & 31;
        float4 v = *(const float4*)(h + (size_t)(n0 + e) * 128 + chunk * 4);
        float4 m = *(const float4*)(mu + chunk * 4);
        float4 s = *(const float4*)(istd + chunk * 4);
        v.x = (v.x - m.x) * s.x; v.y = (v.y - m.y) * s.y;
        v.z = (v.z - m.z) * s.z; v.w = (v.w - m.w) * s.w;
        *(float4*)(sh + e * 128 + chunk * 4) = v;
    }
    if (tid < 128) sw1[tid] = W1[tid];
    else if (tid < 240) sw2[tid - 128] = W2[tid - 128];
    if (tid < 8) sb1[tid] = b1[tid];
    __syncthreads();
    int g = tid >> 5, lane = tid & 31;
    int node = n0 + g;
    for (int idx = lane; idx < 304; idx += 32){
        int c = idx / 38, j = idx % 38;
        float a = sb1[c];
        int base = 3 * j;
        #pragma unroll
        for (int k = 0; k < 16; ++k) a = fmaf(sh[g * 128 + base + k], sw1[c * 16 + k], a);
        so[g * 308 + c * 38 + j] = silu_f(a);
    }
    __syncthreads();
    if (lane < 25){
        float a = b2[0];
        #pragma unroll
        for (int c = 0; c < 8; ++c)
            #pragma unroll
            for (int k = 0; k < 14; ++k)
                a = fmaf(so[g * 308 + c * 38 + lane + k], sw2[c * 14 + k], a);
        float dtv = dt[0];
        out[(size_t)node * 25 + lane] = x[(size_t)node * 25 + 24] + dtv * (float)(lane + 1) * a;
    }
}

extern "C" void kernel_launch(void* const* d_in, const int* in_sizes, int n_in,
                              void* d_out, int out_size, void* d_ws, size_t ws_size,
                              hipStream_t stream){
    (void)in_sizes; (void)n_in; (void)out_size; (void)ws_size;
    const float* x      = (const float*)d_in[0];
    const float* pos    = (const float*)d_in[1];
    const float* vars   = (const float*)d_in[2];
    const float* dt     = (const float*)d_in[3];
    const int*   ei     = (const int*)d_in[4];
    const float* encW1  = (const float*)d_in[5];
    const float* encb1  = (const float*)d_in[6];
    const float* encW2  = (const float*)d_in[7];
    const float* encb2  = (const float*)d_in[8];
    const float* msgW1  = (const float*)d_in[9];
    const float* msgb1  = (const float*)d_in[10];
    const float* msgW2  = (const float*)d_in[11];
    const float* msgb2  = (const float*)d_in[12];
    const float* updW1  = (const float*)d_in[13];
    const float* updb1  = (const float*)d_in[14];
    const float* updW2  = (const float*)d_in[15];
    const float* updb2  = (const float*)d_in[16];
    const float* decW1  = (const float*)d_in[17];
    const float* decb1  = (const float*)d_in[18];
    const float* decW2  = (const float*)d_in[19];
    const float* decb2  = (const float*)d_in[20];
    float* out = (float*)d_out;

    float* ws = (float*)d_ws;
    size_t off = 0;
    float* hA      = ws + off; off += (size_t)N_NODES * 128;
    float* agg     = ws + off; off += (size_t)N_NODES * 128;
    float* sacc    = ws + off; off += 128;          // contiguous with agg for joint memset
    float* qacc    = ws + off; off += 128;
    float* raF     = ws + off; off += (size_t)N_NODES * 128;   // f32 ra
    float* p       = ws + off; off += N_NODES;
    float* invdeg  = ws + off; off += N_NODES;
    float* muArr   = ws + off; off += 6 * 128;
    float* istdArr = ws + off; off += 6 * 128;
    int* deg       = (int*)(ws + off); off += N_NODES;
    unsigned* maxp = (unsigned*)(ws + off); off += 2;
    int* csum      = (int*)(ws + off); off += 256;
    int* coff      = (int*)(ws + off); off += 256;
    int* cursor    = (int*)(ws + off); off += N_NODES;
    int* ssrcS     = (int*)(ws + off); off += N_EDGES;
    int* sdstS     = (int*)(ws + off); off += N_EDGES;
    __bf16* wpack  = (__bf16*)(ws + off); off += (PK_TOTAL + 1) / 2;
    __bf16* rbB    = (__bf16*)(ws + off); off += (size_t)N_NODES * 64;

    __bf16* pra = wpack;
    __bf16* prb = pra + PK_RA;
    __bf16* pm2 = prb + PK_RB;
    __bf16* pu1 = pm2 + PK_M2;
    __bf16* pu2 = pu1 + PK_U1;

    const int* esrc = ei;
    const int* edst = ei + N_EDGES;

    hipMemsetAsync(deg, 0, (size_t)N_NODES * sizeof(int) + sizeof(unsigned), stream);

    k_pack<<<(PK_TOTAL + 255) / 256, 256, 0, stream>>>(msgW1, msgW2, updW1, updW2, wpack);
    k_max<<<256, 256, 0, stream>>>(pos, maxp);
    k_deg<<<N_EDGES / 256, 256, 0, stream>>>(edst, deg);
    k_scan1<<<256, 256, 0, stream>>>(deg, csum);
    k_scan2<<<1, 256, 0, stream>>>(csum, coff);
    k_scan3<<<256, 256, 0, stream>>>(deg, coff, cursor);
    k_scatter<<<N_EDGES / 256, 256, 0, stream>>>(esrc, edst, cursor, ssrcS, sdstS);
    k_prep<<<N_NODES / 256, 256, 0, stream>>>(pos, maxp, deg, p, invdeg);
    k_enc<<<N_NODES / 32, 256, 0, stream>>>(x, p, vars, encW1, encb1, encW2, encb2, hA);

    for (int l = 0; l < N_LAYERS; ++l){
        hipMemsetAsync(agg, 0, ((size_t)N_NODES * 128 + 256) * sizeof(float), stream);
        const float* muPrev   = (l > 0) ? (muArr + (size_t)(l - 1) * 128) : muArr;
        const float* istdPrev = (l > 0) ? (istdArr + (size_t)(l - 1) * 128) : istdArr;
        k_npre<<<N_NODES / 32, 256, 0, stream>>>(hA, x, p, vars, muPrev, istdPrev, (l > 0) ? 1 : 0,
            pra + (size_t)l * 20480, prb + (size_t)l * 20480, msgb1 + l * 128, raF, rbB);
        k_edge3<<<N_EDGES / 64, 256, 0, stream>>>(raF, rbB, ssrcS, sdstS,
            pm2 + (size_t)l * 16384, msgb2 + l * 128, agg);
        k_upd_m<<<N_NODES / 32, 256, 0, stream>>>(hA, agg, vars, invdeg, muPrev, istdPrev, (l > 0) ? 1 : 0,
            pu1 + (size_t)l * 36864, updb1 + l * 128,
            pu2 + (size_t)l * 16384, updb2 + l * 128, sacc, qacc);
        k_statfin<<<1, 128, 0, stream>>>(sacc, qacc, muArr + (size_t)l * 128, istdArr + (size_t)l * 128);
    }

    k_dec<<<N_NODES / 8, 256, 0, stream>>>(hA, x, dt, decW1, decb1, decW2, decb2,
                                           muArr + 5 * 128, istdArr + 5 * 128, out);
}

// Round 5
// 920.670 us; speedup vs baseline: 1.6191x; 1.1990x over previous
//
#include <hip/hip_runtime.h>
#include <math.h>

#define N_NODES 65536
#define N_EDGES 262144
#define N_LAYERS 6
#define T_MAX_F 16.0f
#define EPS_F 1e-5f

typedef float  f32x4  __attribute__((ext_vector_type(4)));
typedef __bf16 bf16x8 __attribute__((ext_vector_type(8)));
typedef __bf16 bf16x4 __attribute__((ext_vector_type(4)));

__device__ __forceinline__ float silu_f(float v){
    return v / (1.0f + __expf(-v));
}

__device__ __forceinline__ f32x4 mfma16(bf16x8 a, bf16x8 b, f32x4 c){
    return __builtin_amdgcn_mfma_f32_16x16x32_bf16(a, b, c, 0, 0, 0);
}

// ---------------- weight prepack ----------------
// B-fragment packed layout per weight: [kb][cb][lane(64)][elem(8)],
// col = cb*16 + (lane&15), k = kb*32 + (lane>>4)*8 + elem.
#define PK_RA (6 * 20480)   // msg W1 dst-side, K=160 (5 kb)
#define PK_RB (6 * 20480)   // msg W1 src-side
#define PK_M2 (6 * 16384)   // msg W2, K=128
#define PK_U1 (6 * 36864)   // upd W1, K=288 pad
#define PK_U2 (6 * 16384)   // upd W2, K=128
#define PK_TOTAL (PK_RA + PK_RB + PK_M2 + PK_U1 + PK_U2)

__global__ __launch_bounds__(256) void k_pack(const float* __restrict__ msgW1, const float* __restrict__ msgW2,
                                              const float* __restrict__ updW1, const float* __restrict__ updW2,
                                              __bf16* __restrict__ out){
    int pg = blockIdx.x * 256 + threadIdx.x;
    if (pg >= PK_TOTAL) return;
    int p = pg;
    int mode; const float* W; int perL;
    if (p < PK_RA){ mode = 0; W = msgW1; perL = 20480; }
    else if ((p -= PK_RA) < PK_RB){ mode = 1; W = msgW1; perL = 20480; }
    else if ((p -= PK_RB) < PK_M2){ mode = 2; W = msgW2; perL = 16384; }
    else if ((p -= PK_M2) < PK_U1){ mode = 3; W = updW1; perL = 36864; }
    else { p -= PK_U1; mode = 4; W = updW2; perL = 16384; }
    int l = p / perL, q = p % perL;
    int elem = q & 7, lane = (q >> 3) & 63, cb = (q >> 9) & 7, kb = q >> 12;
    int col = cb * 16 + (lane & 15);
    int k = kb * 32 + ((lane >> 4) << 3) + elem;
    float v = 0.0f;
    if (mode == 0){
        int r = -1;
        if (k < 128) r = k;
        else if (k < 153) r = 256 + (k - 128);
        else if (k == 153) r = 281;
        else if (k < 158) r = 282 + (k - 154);
        if (r >= 0) v = W[(size_t)l * 286 * 128 + (size_t)r * 128 + col];
    } else if (mode == 1){
        if (k < 128) v = W[(size_t)l * 286 * 128 + (size_t)(128 + k) * 128 + col];
        else if (k < 153) v = -W[(size_t)l * 286 * 128 + (size_t)(256 + (k - 128)) * 128 + col];
        else if (k == 153) v = -W[(size_t)l * 286 * 128 + (size_t)281 * 128 + col];
    } else {
        int Kreal = (mode == 3) ? 260 : 128;
        if (k < Kreal) v = W[(size_t)l * Kreal * 128 + (size_t)k * 128 + col];
    }
    out[pg] = (__bf16)v;
}

// ---------------- small prep kernels ----------------
__global__ __launch_bounds__(256) void k_max(const float* __restrict__ pos, unsigned* __restrict__ outmax){
    __shared__ float s[256];
    int tid = threadIdx.x;
    float m = 0.0f;
    for (int i = blockIdx.x * 256 + tid; i < N_NODES; i += 256 * 256)
        m = fmaxf(m, pos[i]);
    s[tid] = m;
    __syncthreads();
    for (int off = 128; off > 0; off >>= 1){
        if (tid < off) s[tid] = fmaxf(s[tid], s[tid + off]);
        __syncthreads();
    }
    if (tid == 0) atomicMax(outmax, __float_as_uint(s[0]));
}

__global__ __launch_bounds__(256) void k_deg(const int* __restrict__ dst, int* __restrict__ deg){
    int i = blockIdx.x * 256 + threadIdx.x;
    if (i < N_EDGES) atomicAdd(deg + dst[i], 1);
}

__global__ __launch_bounds__(256) void k_prep(const float* __restrict__ pos, const unsigned* __restrict__ maxp,
                                              const int* __restrict__ deg,
                                              float* __restrict__ p, float* __restrict__ invdeg){
    int i = blockIdx.x * 256 + threadIdx.x;
    if (i < N_NODES){
        float mp = __uint_as_float(*maxp);
        p[i] = pos[i] / mp;
        invdeg[i] = 1.0f / fmaxf((float)deg[i], 1.0f);
    }
}

// ---------------- CSR build: scan + scatter ----------------
__global__ __launch_bounds__(256) void k_scan1(const int* __restrict__ deg, int* __restrict__ csum){
    __shared__ int s[256];
    int c = blockIdx.x, t = threadIdx.x;
    s[t] = deg[c * 256 + t];
    __syncthreads();
    for (int o = 128; o > 0; o >>= 1){ if (t < o) s[t] += s[t + o]; __syncthreads(); }
    if (t == 0) csum[c] = s[0];
}

__global__ __launch_bounds__(256) void k_scan2(const int* __restrict__ csum, int* __restrict__ coff){
    __shared__ int s[256];
    int t = threadIdx.x;
    s[t] = csum[t];
    __syncthreads();
    for (int o = 1; o < 256; o <<= 1){
        int v = (t >= o) ? s[t - o] : 0;
        __syncthreads();
        s[t] += v;
        __syncthreads();
    }
    coff[t] = s[t] - csum[t];   // exclusive
}

__global__ __launch_bounds__(256) void k_scan3(const int* __restrict__ deg, const int* __restrict__ coff,
                                               int* __restrict__ cursor){
    __shared__ int s[256];
    int c = blockIdx.x, t = threadIdx.x;
    int d = deg[c * 256 + t];
    s[t] = d;
    __syncthreads();
    for (int o = 1; o < 256; o <<= 1){
        int v = (t >= o) ? s[t - o] : 0;
        __syncthreads();
        s[t] += v;
        __syncthreads();
    }
    cursor[c * 256 + t] = coff[c] + s[t] - d;
}

__global__ __launch_bounds__(256) void k_scatter(const int* __restrict__ esrc, const int* __restrict__ edst,
                                                 int* __restrict__ cursor,
                                                 int* __restrict__ ssrcS, int* __restrict__ sdstS){
    int e = blockIdx.x * 256 + threadIdx.x;
    if (e < N_EDGES){
        int d = edst[e];
        int slot = atomicAdd(cursor + d, 1);
        ssrcS[slot] = esrc[e];
        sdstS[slot] = d;
    }
}

// ---------------- encoder (f32, runs once) ----------------
__device__ __forceinline__ void gemm44(const float* A, int lda, const float* __restrict__ W,
                                       int kq_begin, int kq_end, int r0, int c0, float acc[4][4]){
    for (int kq = kq_begin; kq < kq_end; ++kq){
        int k = kq * 4;
        float a[4][4], w[4][4];
        #pragma unroll
        for (int i = 0; i < 4; ++i){
            float4 v = *(const float4*)(A + (r0 + i) * lda + k);
            a[i][0] = v.x; a[i][1] = v.y; a[i][2] = v.z; a[i][3] = v.w;
        }
        #pragma unroll
        for (int kk = 0; kk < 4; ++kk){
            float4 v = *(const float4*)(W + (k + kk) * 128 + c0);
            w[kk][0] = v.x; w[kk][1] = v.y; w[kk][2] = v.z; w[kk][3] = v.w;
        }
        #pragma unroll
        for (int kk = 0; kk < 4; ++kk)
            #pragma unroll
            for (int i = 0; i < 4; ++i)
                #pragma unroll
                for (int j = 0; j < 4; ++j)
                    acc[i][j] = fmaf(a[i][kk], w[kk][j], acc[i][j]);
    }
}

__global__ __launch_bounds__(256) void k_enc(const float* __restrict__ x, const float* __restrict__ p,
                                             const float* __restrict__ vars,
                                             const float* __restrict__ W1, const float* __restrict__ b1,
                                             const float* __restrict__ W2, const float* __restrict__ b2,
                                             float* __restrict__ hA){
    __shared__ __align__(16) float sin_[32 * 32];
    __shared__ __align__(16) float sw1[32 * 128];
    __shared__ __align__(16) float sy[32 * 128];
    int tid = threadIdx.x;
    int n0 = blockIdx.x * 32;
    for (int i = tid; i < 32 * 32; i += 256){
        int e = i >> 5, k = i & 31;
        int node = n0 + e;
        float v;
        if (k < 25)       v = x[node * 25 + k];
        else if (k == 25) v = p[node];
        else if (k == 26) v = vars[node * 4 + 3] * (1.0f / T_MAX_F);
        else if (k < 30)  v = vars[node * 4 + (k - 27)];
        else              v = 0.0f;
        sin_[e * 32 + k] = v;
    }
    for (int i = tid; i < 32 * 128; i += 256){
        int r = i >> 7;
        sw1[i] = (r < 30) ? W1[i] : 0.0f;
    }
    __syncthreads();
    int c0 = (tid & 31) * 4, r0 = (tid >> 5) * 4;
    float acc[4][4] = {};
    gemm44(sin_, 32, sw1, 0, 8, r0, c0, acc);
    float4 bv = *(const float4*)(b1 + c0);
    float b_[4] = {bv.x, bv.y, bv.z, bv.w};
    #pragma unroll
    for (int i = 0; i < 4; ++i){
        float4 o;
        o.x = silu_f(acc[i][0] + b_[0]);
        o.y = silu_f(acc[i][1] + b_[1]);
        o.z = silu_f(acc[i][2] + b_[2]);
        o.w = silu_f(acc[i][3] + b_[3]);
        *(float4*)(sy + (r0 + i) * 128 + c0) = o;
    }
    __syncthreads();
    float acc2[4][4] = {};
    gemm44(sy, 128, W2, 0, 32, r0, c0, acc2);
    float4 b2v = *(const float4*)(b2 + c0);
    float bb[4] = {b2v.x, b2v.y, b2v.z, b2v.w};
    #pragma unroll
    for (int i = 0; i < 4; ++i){
        float4 o;
        o.x = silu_f(acc2[i][0] + bb[0]);
        o.y = silu_f(acc2[i][1] + bb[1]);
        o.z = silu_f(acc2[i][2] + bb[2]);
        o.w = silu_f(acc2[i][3] + bb[3]);
        *(float4*)(hA + (size_t)(n0 + r0 + i) * 128 + c0) = o;
    }
}

// ---------------- node precompute: on-the-fly LN + ra/rb GEMM; zeroes agg ----------------
__global__ __launch_bounds__(256) void k_npre(const float* __restrict__ hA, const float* __restrict__ x,
                                              const float* __restrict__ p, const float* __restrict__ vars,
                                              const float* __restrict__ mu, const float* __restrict__ istd,
                                              int apply_ln,
                                              const __bf16* __restrict__ Wra, const __bf16* __restrict__ Wrb,
                                              const float* __restrict__ b1,
                                              float* __restrict__ raO, __bf16* __restrict__ rbO,
                                              float* __restrict__ aggZ, float* __restrict__ saccZ){
    __shared__ __align__(16) __bf16 sA[10 * 64 * 8];
    __shared__ __align__(16) float sOut[32 * 264];
    int tid = threadIdx.x;
    int n0 = blockIdx.x * 32;
    // zero agg rows + (block 0) sacc/qacc
    {
        float4 z4 = {0.f, 0.f, 0.f, 0.f};
        #pragma unroll
        for (int it = 0; it < 4; ++it){
            int i = tid + it * 256;
            int e = i >> 5, ch = i & 31;
            *(float4*)(aggZ + (size_t)(n0 + e) * 128 + ch * 4) = z4;
        }
        if (blockIdx.x == 0) saccZ[tid] = 0.f;
    }
    #pragma unroll
    for (int it = 0; it < 3; ++it){
        int j = tid + it * 256;
        if (j < 640){
            int f = j >> 6, lane = j & 63;
            int kb = f >> 1, mt = f & 1;
            int e = (lane & 15) + mt * 16, kh = lane >> 4;
            int node = n0 + e;
            bf16x8 o;
            if (kb < 4){
                int k0 = kb * 32 + kh * 8;
                float4 v0 = *(const float4*)(hA + (size_t)node * 128 + k0);
                float4 v1 = *(const float4*)(hA + (size_t)node * 128 + k0 + 4);
                if (apply_ln){
                    float4 m0 = *(const float4*)(mu + k0),   m1 = *(const float4*)(mu + k0 + 4);
                    float4 s0 = *(const float4*)(istd + k0), s1 = *(const float4*)(istd + k0 + 4);
                    v0.x = (v0.x - m0.x) * s0.x; v0.y = (v0.y - m0.y) * s0.y;
                    v0.z = (v0.z - m0.z) * s0.z; v0.w = (v0.w - m0.w) * s0.w;
                    v1.x = (v1.x - m1.x) * s1.x; v1.y = (v1.y - m1.y) * s1.y;
                    v1.z = (v1.z - m1.z) * s1.z; v1.w = (v1.w - m1.w) * s1.w;
                }
                o[0] = (__bf16)v0.x; o[1] = (__bf16)v0.y; o[2] = (__bf16)v0.z; o[3] = (__bf16)v0.w;
                o[4] = (__bf16)v1.x; o[5] = (__bf16)v1.y; o[6] = (__bf16)v1.z; o[7] = (__bf16)v1.w;
            } else {
                #pragma unroll
                for (int jj = 0; jj < 8; ++jj){
                    int fk = kh * 8 + jj;
                    float v;
                    if (fk < 25)       v = x[node * 25 + fk];
                    else if (fk == 25) v = p[node];
                    else if (fk < 30)  v = vars[node * 4 + (fk - 26)];
                    else               v = 0.0f;
                    o[jj] = (__bf16)v;
                }
            }
            *(bf16x8*)(sA + (f * 64 + lane) * 8) = o;
        }
    }
    __syncthreads();
    int w = tid >> 6, lane = tid & 63;
    int clo = lane & 15, rhi = lane >> 4;
    f32x4 z = {0.f, 0.f, 0.f, 0.f};
    f32x4 aR[2][2] = {{z, z}, {z, z}};
    f32x4 aB[2][2] = {{z, z}, {z, z}};
    #pragma unroll
    for (int kb = 0; kb < 5; ++kb){
        bf16x8 a0 = *(bf16x8*)(sA + ((kb * 2 + 0) * 64 + lane) * 8);
        bf16x8 a1 = *(bf16x8*)(sA + ((kb * 2 + 1) * 64 + lane) * 8);
        bf16x8 wr0 = *(const bf16x8*)(Wra + (size_t)((kb * 8 + 2 * w)     * 64 + lane) * 8);
        bf16x8 wr1 = *(const bf16x8*)(Wra + (size_t)((kb * 8 + 2 * w + 1) * 64 + lane) * 8);
        bf16x8 wb0 = *(const bf16x8*)(Wrb + (size_t)((kb * 8 + 2 * w)     * 64 + lane) * 8);
        bf16x8 wb1 = *(const bf16x8*)(Wrb + (size_t)((kb * 8 + 2 * w + 1) * 64 + lane) * 8);
        aR[0][0] = mfma16(a0, wr0, aR[0][0]);
        aR[0][1] = mfma16(a0, wr1, aR[0][1]);
        aR[1][0] = mfma16(a1, wr0, aR[1][0]);
        aR[1][1] = mfma16(a1, wr1, aR[1][1]);
        aB[0][0] = mfma16(a0, wb0, aB[0][0]);
        aB[0][1] = mfma16(a0, wb1, aB[0][1]);
        aB[1][0] = mfma16(a1, wb0, aB[1][0]);
        aB[1][1] = mfma16(a1, wb1, aB[1][1]);
    }
    #pragma unroll
    for (int nf = 0; nf < 2; ++nf){
        int col = (2 * w + nf) * 16 + clo;
        float bv = b1[col];
        #pragma unroll
        for (int mt = 0; mt < 2; ++mt)
            #pragma unroll
            for (int i = 0; i < 4; ++i){
                int e = mt * 16 + rhi * 4 + i;
                sOut[e * 264 + col]       = aR[mt][nf][i] + bv;
                sOut[e * 264 + 128 + col] = aB[mt][nf][i];
            }
    }
    __syncthreads();
    #pragma unroll
    for (int it = 0; it < 4; ++it){
        int j = tid + it * 256;
        int row = j >> 5, c8 = j & 31;
        const float* src = sOut + row * 264 + c8 * 8;
        if (c8 < 16){
            float4 v0 = *(const float4*)(src);
            float4 v1 = *(const float4*)(src + 4);
            float* dstp = raO + (size_t)(n0 + row) * 128 + c8 * 8;
            *(float4*)(dstp)     = v0;
            *(float4*)(dstp + 4) = v1;
        } else {
            bf16x8 o;
            #pragma unroll
            for (int t = 0; t < 8; ++t) o[t] = (__bf16)src[t];
            *(bf16x8*)(rbO + (size_t)(n0 + row) * 128 + (c8 - 16) * 8) = o;
        }
    }
}

// ---------------- edge (CSR-sorted): y1 = silu(ra[dst]+rb[src]); m = silu(y1@W2+b2);
// segmented LDS reduction by dst, then one atomicAdd per (segment, col). ----------------
__global__ __launch_bounds__(256) void k_edge3(const float* __restrict__ ra, const __bf16* __restrict__ rb,
                                               const int* __restrict__ ssrcS, const int* __restrict__ sdstS,
                                               const __bf16* __restrict__ Wp2, const float* __restrict__ bias2,
                                               float* __restrict__ agg){
    __shared__ __align__(16) unsigned char smem[64 * 128 * 4];
    __shared__ int sd[64], ss[64];
    __bf16* sA   = (__bf16*)smem;
    float*  msum = (float*)smem;
    int tid = threadIdx.x;
    int e0 = blockIdx.x * 64;
    if (tid < 64){ sd[tid] = sdstS[e0 + tid]; ss[tid] = ssrcS[e0 + tid]; }
    __syncthreads();
    #pragma unroll
    for (int it = 0; it < 4; ++it){
        int j = tid + it * 256;
        int f = j >> 6, lane = j & 63;
        int kb = f >> 2, mt = f & 3;
        int e = (lane & 15) + mt * 16;
        int k0 = kb * 32 + (lane >> 4) * 8;
        const float* rap = ra + (size_t)sd[e] * 128 + k0;
        float4 v0 = *(const float4*)(rap);
        float4 v1 = *(const float4*)(rap + 4);
        bf16x8 vb = *(const bf16x8*)(rb + (size_t)ss[e] * 128 + k0);
        bf16x8 o;
        o[0] = (__bf16)silu_f(v0.x + (float)vb[0]);
        o[1] = (__bf16)silu_f(v0.y + (float)vb[1]);
        o[2] = (__bf16)silu_f(v0.z + (float)vb[2]);
        o[3] = (__bf16)silu_f(v0.w + (float)vb[3]);
        o[4] = (__bf16)silu_f(v1.x + (float)vb[4]);
        o[5] = (__bf16)silu_f(v1.y + (float)vb[5]);
        o[6] = (__bf16)silu_f(v1.z + (float)vb[6]);
        o[7] = (__bf16)silu_f(v1.w + (float)vb[7]);
        *(bf16x8*)(sA + (f * 64 + lane) * 8) = o;
    }
    __syncthreads();
    int w = tid >> 6, lane = tid & 63;
    int cb0 = 2 * w, clo = lane & 15, rhi = lane >> 4;
    f32x4 z = {0.f, 0.f, 0.f, 0.f};
    f32x4 acc[4][2] = {{z, z}, {z, z}, {z, z}, {z, z}};
    #pragma unroll
    for (int kb = 0; kb < 4; ++kb){
        bf16x8 a0 = *(bf16x8*)(sA + ((kb * 4 + 0) * 64 + lane) * 8);
        bf16x8 a1 = *(bf16x8*)(sA + ((kb * 4 + 1) * 64 + lane) * 8);
        bf16x8 a2 = *(bf16x8*)(sA + ((kb * 4 + 2) * 64 + lane) * 8);
        bf16x8 a3 = *(bf16x8*)(sA + ((kb * 4 + 3) * 64 + lane) * 8);
        bf16x8 w0 = *(const bf16x8*)(Wp2 + (size_t)((kb * 8 + cb0)     * 64 + lane) * 8);
        bf16x8 w1 = *(const bf16x8*)(Wp2 + (size_t)((kb * 8 + cb0 + 1) * 64 + lane) * 8);
        acc[0][0] = mfma16(a0, w0, acc[0][0]);
        acc[0][1] = mfma16(a0, w1, acc[0][1]);
        acc[1][0] = mfma16(a1, w0, acc[1][0]);
        acc[1][1] = mfma16(a1, w1, acc[1][1]);
        acc[2][0] = mfma16(a2, w0, acc[2][0]);
        acc[2][1] = mfma16(a2, w1, acc[2][1]);
        acc[3][0] = mfma16(a3, w0, acc[3][0]);
        acc[3][1] = mfma16(a3, w1, acc[3][1]);
    }
    __syncthreads();
    #pragma unroll
    for (int nf = 0; nf < 2; ++nf){
        int col = (cb0 + nf) * 16 + clo;
        float bv = bias2[col];
        #pragma unroll
        for (int mt = 0; mt < 4; ++mt)
            #pragma unroll
            for (int i = 0; i < 4; ++i){
                int row = mt * 16 + rhi * 4 + i;
                msum[row * 128 + col] = silu_f(acc[mt][nf][i] + bv);
            }
    }
    __syncthreads();
    int col = tid & 127, half = tid >> 7;
    int base = half * 32;
    float run = 0.0f;
    for (int r = 0; r < 32; ++r){
        int row = base + r;
        run += msum[row * 128 + col];
        bool flush = (r == 31) || (sd[row + 1] != sd[row]);
        if (flush){
            atomicAdd(agg + (size_t)sd[row] * 128 + col, run);
            run = 0.0f;
        }
    }
}

// ---------------- node update MLP v2: M=64, fragment-direct staging, fused stats ----------------
__global__ __launch_bounds__(256) void k_upd_m(float* __restrict__ hA, const float* __restrict__ agg,
                                               const float* __restrict__ vars, const float* __restrict__ invdeg,
                                               const float* __restrict__ mu, const float* __restrict__ istd,
                                               int apply_ln,
                                               const __bf16* __restrict__ Wp1, const float* __restrict__ bias1,
                                               const __bf16* __restrict__ Wp2, const float* __restrict__ bias2,
                                               float* __restrict__ sacc, float* __restrict__ qacc){
    // sA1: 36 frag-groups (9 kb x 4 mt) x 64 lanes x bf16x8 = 36 KB.
    // zb (y1, [64][152] bf16, 19 KB) overlays sA1 after GEMM1.
    __shared__ __align__(16) __bf16 sA1[36 * 64 * 8];
    __bf16* zb = sA1;
    int tid = threadIdx.x;
    int n0 = blockIdx.x * 64;
    #pragma unroll
    for (int it = 0; it < 9; ++it){
        int idx = tid + it * 256;
        int f = idx >> 6, lane = idx & 63;
        int kb = f >> 2, mt = f & 3;
        int row = (lane & 15) + mt * 16;
        int node = n0 + row;
        int k0 = kb * 32 + ((lane >> 4) << 3);
        bf16x8 o;
        if (k0 < 128){
            float4 v0 = *(const float4*)(hA + (size_t)node * 128 + k0);
            float4 v1 = *(const float4*)(hA + (size_t)node * 128 + k0 + 4);
            if (apply_ln){
                float4 m0 = *(const float4*)(mu + k0),   m1 = *(const float4*)(mu + k0 + 4);
                float4 s0 = *(const float4*)(istd + k0), s1 = *(const float4*)(istd + k0 + 4);
                v0.x = (v0.x - m0.x) * s0.x; v0.y = (v0.y - m0.y) * s0.y;
                v0.z = (v0.z - m0.z) * s0.z; v0.w = (v0.w - m0.w) * s0.w;
                v1.x = (v1.x - m1.x) * s1.x; v1.y = (v1.y - m1.y) * s1.y;
                v1.z = (v1.z - m1.z) * s1.z; v1.w = (v1.w - m1.w) * s1.w;
            }
            o[0] = (__bf16)v0.x; o[1] = (__bf16)v0.y; o[2] = (__bf16)v0.z; o[3] = (__bf16)v0.w;
            o[4] = (__bf16)v1.x; o[5] = (__bf16)v1.y; o[6] = (__bf16)v1.z; o[7] = (__bf16)v1.w;
        } else if (k0 < 256){
            int g0 = k0 - 128;
            float4 v0 = *(const float4*)(agg + (size_t)node * 128 + g0);
            float4 v1 = *(const float4*)(agg + (size_t)node * 128 + g0 + 4);
            float s = invdeg[node];
            o[0] = (__bf16)(v0.x * s); o[1] = (__bf16)(v0.y * s); o[2] = (__bf16)(v0.z * s); o[3] = (__bf16)(v0.w * s);
            o[4] = (__bf16)(v1.x * s); o[5] = (__bf16)(v1.y * s); o[6] = (__bf16)(v1.z * s); o[7] = (__bf16)(v1.w * s);
        } else {
            int fk = k0 - 256;
            #pragma unroll
            for (int jj = 0; jj < 8; ++jj){
                int kk = fk + jj;
                o[jj] = (__bf16)((kk < 4) ? vars[(size_t)node * 4 + kk] : 0.0f);
            }
        }
        *(bf16x8*)(sA1 + (size_t)idx * 8) = o;
    }
    __syncthreads();
    int w = tid >> 6, lane = tid & 63;
    int cb0 = 2 * w, clo = lane & 15, rhi = lane >> 4;
    f32x4 z = {0.f, 0.f, 0.f, 0.f};
    f32x4 acc[4][2] = {{z, z}, {z, z}, {z, z}, {z, z}};
    #pragma unroll
    for (int kb = 0; kb < 9; ++kb){
        bf16x8 w0 = *(const bf16x8*)(Wp1 + (size_t)((kb * 8 + cb0)     * 64 + lane) * 8);
        bf16x8 w1 = *(const bf16x8*)(Wp1 + (size_t)((kb * 8 + cb0 + 1) * 64 + lane) * 8);
        #pragma unroll
        for (int mt = 0; mt < 4; ++mt){
            bf16x8 a = *(bf16x8*)(sA1 + ((kb * 4 + mt) * 64 + lane) * 8);
            acc[mt][0] = mfma16(a, w0, acc[mt][0]);
            acc[mt][1] = mfma16(a, w1, acc[mt][1]);
        }
    }
    __syncthreads();   // all sA1 reads done before zb overlay
    #pragma unroll
    for (int nf = 0; nf < 2; ++nf){
        int col = (cb0 + nf) * 16 + clo;
        float bv = bias1[col];
        #pragma unroll
        for (int mt = 0; mt < 4; ++mt)
            #pragma unroll
            for (int i = 0; i < 4; ++i){
                int row = mt * 16 + rhi * 4 + i;
                zb[row * 152 + col] = (__bf16)silu_f(acc[mt][nf][i] + bv);
            }
    }
    __syncthreads();
    f32x4 acc2[4][2] = {{z, z}, {z, z}, {z, z}, {z, z}};
    #pragma unroll
    for (int kb = 0; kb < 4; ++kb){
        bf16x8 w0 = *(const bf16x8*)(Wp2 + (size_t)((kb * 8 + cb0)     * 64 + lane) * 8);
        bf16x8 w1 = *(const bf16x8*)(Wp2 + (size_t)((kb * 8 + cb0 + 1) * 64 + lane) * 8);
        int k0 = kb * 32 + ((lane >> 4) << 3);
        #pragma unroll
        for (int mt = 0; mt < 4; ++mt){
            int row = (lane & 15) + mt * 16;
            bf16x8 a = *(bf16x8*)(zb + row * 152 + k0);
            acc2[mt][0] = mfma16(a, w0, acc2[mt][0]);
            acc2[mt][1] = mfma16(a, w1, acc2[mt][1]);
        }
    }
    float sm[2] = {0.f, 0.f}, sq[2] = {0.f, 0.f};
    #pragma unroll
    for (int nf = 0; nf < 2; ++nf){
        int col = (cb0 + nf) * 16 + clo;
        float bv = bias2[col];
        float muv = apply_ln ? mu[col] : 0.0f;
        float sdv = apply_ln ? istd[col] : 1.0f;
        #pragma unroll
        for (int mt = 0; mt < 4; ++mt)
            #pragma unroll
            for (int i = 0; i < 4; ++i){
                int row = mt * 16 + rhi * 4 + i;
                size_t idx = (size_t)(n0 + row) * 128 + col;
                float u = silu_f(acc2[mt][nf][i] + bv);
                float hln = (hA[idx] - muv) * sdv;
                float hv = hln + u;
                hA[idx] = hv;
                sm[nf] += hv; sq[nf] += hv * hv;
            }
    }
    #pragma unroll
    for (int nf = 0; nf < 2; ++nf){
        float s = sm[nf], q = sq[nf];
        s += __shfl_xor(s, 16); q += __shfl_xor(q, 16);
        s += __shfl_xor(s, 32); q += __shfl_xor(q, 32);
        if (rhi == 0){
            int col = (cb0 + nf) * 16 + clo;
            atomicAdd(sacc + col, s);
            atomicAdd(qacc + col, q);
        }
    }
}

__global__ __launch_bounds__(128) void k_statfin(const float* __restrict__ sacc, const float* __restrict__ qacc,
                                                 float* __restrict__ mu, float* __restrict__ istd){
    int c = threadIdx.x;
    float m = sacc[c] * (1.0f / N_NODES);
    float v = qacc[c] * (1.0f / N_NODES) - m * m;
    mu[c] = m;
    istd[c] = rsqrtf(v + EPS_F);
}

// ---------------- decoder v2 (f32 exact): register sliding-window convs ----------------
#define DECNB 16
__global__ __launch_bounds__(256) void k_dec(const float* __restrict__ h, const float* __restrict__ x,
                                             const float* __restrict__ dt,
                                             const float* __restrict__ W1, const float* __restrict__ b1,
                                             const float* __restrict__ W2, const float* __restrict__ b2,
                                             const float* __restrict__ mu, const float* __restrict__ istd,
                                             float* __restrict__ out){
    __shared__ __align__(16) float sh[DECNB * 132];
    __shared__ __align__(16) float so[DECNB * 312];
    __shared__ float pp[DECNB * 8 * 26];
    __shared__ float sw1[128], sw2[112], sb1[8];
    int tid = threadIdx.x;
    int n0 = blockIdx.x * DECNB;
    for (int i = tid; i < DECNB * 32; i += 256){
        int g = i >> 5, chunk = i & 31;
        float4 v = *(const float4*)(h + (size_t)(n0 + g) * 128 + chunk * 4);
        float4 m = *(const float4*)(mu + chunk * 4);
        float4 s = *(const float4*)(istd + chunk * 4);
        v.x = (v.x - m.x) * s.x; v.y = (v.y - m.y) * s.y;
        v.z = (v.z - m.z) * s.z; v.w = (v.w - m.w) * s.w;
        *(float4*)(sh + g * 132 + chunk * 4) = v;
    }
    if (tid < 128) sw1[tid] = W1[tid];
    else if (tid < 240) sw2[tid - 128] = W2[tid - 128];
    if (tid < 8) sb1[tid] = b1[tid];
    __syncthreads();
    // phase 1: conv1, thread = (node g, channel c, j-half)
    {
        int g = tid >> 4, c = (tid >> 1) & 7, jh = tid & 1;
        int j0 = jh * 19;
        float w[16];
        #pragma unroll
        for (int k = 0; k < 16; ++k) w[k] = sw1[c * 16 + k];
        float bc = sb1[c];
        float win[16];
        #pragma unroll
        for (int k = 0; k < 16; ++k) win[k] = sh[g * 132 + 3 * j0 + k];
        #pragma unroll
        for (int j = 0; j < 19; ++j){
            float a = bc;
            #pragma unroll
            for (int k = 0; k < 16; ++k) a = fmaf(win[k], w[k], a);
            so[g * 312 + c * 38 + j0 + j] = silu_f(a);
            if (j < 18){
                #pragma unroll
                for (int k = 0; k < 13; ++k) win[k] = win[k + 3];
                int base = g * 132 + 3 * (j0 + j + 1) + 13;
                win[13] = sh[base]; win[14] = sh[base + 1]; win[15] = sh[base + 2];
            }
        }
    }
    __syncthreads();
    // phase 2: conv2 partials, thread = (node g, channel c, t-half)
    {
        int g = tid >> 4, c = (tid >> 1) & 7, th = tid & 1;
        int t0 = th * 13;
        int nt = th ? 12 : 13;
        float w[14];
        #pragma unroll
        for (int k = 0; k < 14; ++k) w[k] = sw2[c * 14 + k];
        float win[14];
        #pragma unroll
        for (int k = 0; k < 14; ++k) win[k] = so[g * 312 + c * 38 + t0 + k];
        #pragma unroll
        for (int t = 0; t < 13; ++t){
            if (t < nt){
                float a = 0.0f;
                #pragma unroll
                for (int k = 0; k < 14; ++k) a = fmaf(win[k], w[k], a);
                pp[(g * 8 + c) * 26 + t0 + t] = a;
            }
            if (t + 1 < nt){
                #pragma unroll
                for (int k = 0; k < 13; ++k) win[k] = win[k + 1];
                win[13] = so[g * 312 + c * 38 + t0 + t + 14];
            }
        }
    }
    __syncthreads();
    float dtv = dt[0];
    for (int i = tid; i < DECNB * 25; i += 256){
        int g = i / 25, t = i % 25;
        float a = b2[0];
        #pragma unroll
        for (int c = 0; c < 8; ++c) a += pp[(g * 8 + c) * 26 + t];
        out[(size_t)(n0 + g) * 25 + t] = x[(size_t)(n0 + g) * 25 + 24] + dtv * (float)(t + 1) * a;
    }
}

extern "C" void kernel_launch(void* const* d_in, const int* in_sizes, int n_in,
                              void* d_out, int out_size, void* d_ws, size_t ws_size,
                              hipStream_t stream){
    (void)in_sizes; (void)n_in; (void)out_size; (void)ws_size;
    const float* x      = (const float*)d_in[0];
    const float* pos    = (const float*)d_in[1];
    const float* vars   = (const float*)d_in[2];
    const float* dt     = (const float*)d_in[3];
    const int*   ei     = (const int*)d_in[4];
    const float* encW1  = (const float*)d_in[5];
    const float* encb1  = (const float*)d_in[6];
    const float* encW2  = (const float*)d_in[7];
    const float* encb2  = (const float*)d_in[8];
    const float* msgW1  = (const float*)d_in[9];
    const float* msgb1  = (const float*)d_in[10];
    const float* msgW2  = (const float*)d_in[11];
    const float* msgb2  = (const float*)d_in[12];
    const float* updW1  = (const float*)d_in[13];
    const float* updb1  = (const float*)d_in[14];
    const float* updW2  = (const float*)d_in[15];
    const float* updb2  = (const float*)d_in[16];
    const float* decW1  = (const float*)d_in[17];
    const float* decb1  = (const float*)d_in[18];
    const float* decW2  = (const float*)d_in[19];
    const float* decb2  = (const float*)d_in[20];
    float* out = (float*)d_out;

    float* ws = (float*)d_ws;
    size_t off = 0;
    float* hA      = ws + off; off += (size_t)N_NODES * 128;
    float* agg     = ws + off; off += (size_t)N_NODES * 128;
    float* sacc    = ws + off; off += 128;
    float* qacc    = ws + off; off += 128;
    float* raF     = ws + off; off += (size_t)N_NODES * 128;
    float* p       = ws + off; off += N_NODES;
    float* invdeg  = ws + off; off += N_NODES;
    float* muArr   = ws + off; off += 6 * 128;
    float* istdArr = ws + off; off += 6 * 128;
    int* deg       = (int*)(ws + off); off += N_NODES;
    unsigned* maxp = (unsigned*)(ws + off); off += 2;
    int* csum      = (int*)(ws + off); off += 256;
    int* coff      = (int*)(ws + off); off += 256;
    int* cursor    = (int*)(ws + off); off += N_NODES;
    int* ssrcS     = (int*)(ws + off); off += N_EDGES;
    int* sdstS     = (int*)(ws + off); off += N_EDGES;
    __bf16* wpack  = (__bf16*)(ws + off); off += (PK_TOTAL + 1) / 2;
    __bf16* rbB    = (__bf16*)(ws + off); off += (size_t)N_NODES * 64;

    __bf16* pra = wpack;
    __bf16* prb = pra + PK_RA;
    __bf16* pm2 = prb + PK_RB;
    __bf16* pu1 = pm2 + PK_M2;
    __bf16* pu2 = pu1 + PK_U1;

    const int* esrc = ei;
    const int* edst = ei + N_EDGES;

    hipMemsetAsync(deg, 0, (size_t)N_NODES * sizeof(int) + sizeof(unsigned), stream);

    k_pack<<<(PK_TOTAL + 255) / 256, 256, 0, stream>>>(msgW1, msgW2, updW1, updW2, wpack);
    k_max<<<256, 256, 0, stream>>>(pos, maxp);
    k_deg<<<N_EDGES / 256, 256, 0, stream>>>(edst, deg);
    k_scan1<<<256, 256, 0, stream>>>(deg, csum);
    k_scan2<<<1, 256, 0, stream>>>(csum, coff);
    k_scan3<<<256, 256, 0, stream>>>(deg, coff, cursor);
    k_scatter<<<N_EDGES / 256, 256, 0, stream>>>(esrc, edst, cursor, ssrcS, sdstS);
    k_prep<<<N_NODES / 256, 256, 0, stream>>>(pos, maxp, deg, p, invdeg);
    k_enc<<<N_NODES / 32, 256, 0, stream>>>(x, p, vars, encW1, encb1, encW2, encb2, hA);

    for (int l = 0; l < N_LAYERS; ++l){
        const float* muPrev   = (l > 0) ? (muArr + (size_t)(l - 1) * 128) : muArr;
        const float* istdPrev = (l > 0) ? (istdArr + (size_t)(l - 1) * 128) : istdArr;
        k_npre<<<N_NODES / 32, 256, 0, stream>>>(hA, x, p, vars, muPrev, istdPrev, (l > 0) ? 1 : 0,
            pra + (size_t)l * 20480, prb + (size_t)l * 20480, msgb1 + l * 128, raF, rbB, agg, sacc);
        k_edge3<<<N_EDGES / 64, 256, 0, stream>>>(raF, rbB, ssrcS, sdstS,
            pm2 + (size_t)l * 16384, msgb2 + l * 128, agg);
        k_upd_m<<<N_NODES / 64, 256, 0, stream>>>(hA, agg, vars, invdeg, muPrev, istdPrev, (l > 0) ? 1 : 0,
            pu1 + (size_t)l * 36864, updb1 + l * 128,
            pu2 + (size_t)l * 16384, updb2 + l * 128, sacc, qacc);
        k_statfin<<<1, 128, 0, stream>>>(sacc, qacc, muArr + (size_t)l * 128, istdArr + (size_t)l * 128);
    }

    k_dec<<<N_NODES / DECNB, 256, 0, stream>>>(hA, x, dt, decW1, decb1, decW2, decb2,
                                               muArr + 5 * 128, istdArr + 5 * 128, out);
}

// Round 7
// 877.421 us; speedup vs baseline: 1.6989x; 1.0493x over previous
//
#include <hip/hip_runtime.h>
#include <math.h>

#define N_NODES 65536
#define N_EDGES 262144
#define N_LAYERS 6
#define T_MAX_F 16.0f
#define EPS_F 1e-5f

typedef float  f32x4  __attribute__((ext_vector_type(4)));
typedef __bf16 bf16x8 __attribute__((ext_vector_type(8)));

__device__ __forceinline__ float silu_f(float v){
    return v / (1.0f + __expf(-v));
}

__device__ __forceinline__ f32x4 mfma16(bf16x8 a, bf16x8 b, f32x4 c){
    return __builtin_amdgcn_mfma_f32_16x16x32_bf16(a, b, c, 0, 0, 0);
}

// ---------------- weight prepack ----------------
// B-fragment packed layout per weight: [kb][cb][lane(64)][elem(8)],
// col = cb*16 + (lane&15), k = kb*32 + (lane>>4)*8 + elem.
#define PK_RA (6 * 20480)   // msg W1 dst-side, K=160 (5 kb)
#define PK_RB (6 * 20480)   // msg W1 src-side
#define PK_M2 (6 * 16384)   // msg W2, K=128
#define PK_U1 (6 * 36864)   // upd W1, K=288 pad
#define PK_U2 (6 * 16384)   // upd W2, K=128
#define PK_TOTAL (PK_RA + PK_RB + PK_M2 + PK_U1 + PK_U2)

__global__ __launch_bounds__(256) void k_pack(const float* __restrict__ msgW1, const float* __restrict__ msgW2,
                                              const float* __restrict__ updW1, const float* __restrict__ updW2,
                                              __bf16* __restrict__ out){
    int pg = blockIdx.x * 256 + threadIdx.x;
    if (pg >= PK_TOTAL) return;
    int p = pg;
    int mode; const float* W; int perL;
    if (p < PK_RA){ mode = 0; W = msgW1; perL = 20480; }
    else if ((p -= PK_RA) < PK_RB){ mode = 1; W = msgW1; perL = 20480; }
    else if ((p -= PK_RB) < PK_M2){ mode = 2; W = msgW2; perL = 16384; }
    else if ((p -= PK_M2) < PK_U1){ mode = 3; W = updW1; perL = 36864; }
    else { p -= PK_U1; mode = 4; W = updW2; perL = 16384; }
    int l = p / perL, q = p % perL;
    int elem = q & 7, lane = (q >> 3) & 63, cb = (q >> 9) & 7, kb = q >> 12;
    int col = cb * 16 + (lane & 15);
    int k = kb * 32 + ((lane >> 4) << 3) + elem;
    float v = 0.0f;
    if (mode == 0){
        int r = -1;
        if (k < 128) r = k;
        else if (k < 153) r = 256 + (k - 128);
        else if (k == 153) r = 281;
        else if (k < 158) r = 282 + (k - 154);
        if (r >= 0) v = W[(size_t)l * 286 * 128 + (size_t)r * 128 + col];
    } else if (mode == 1){
        if (k < 128) v = W[(size_t)l * 286 * 128 + (size_t)(128 + k) * 128 + col];
        else if (k < 153) v = -W[(size_t)l * 286 * 128 + (size_t)(256 + (k - 128)) * 128 + col];
        else if (k == 153) v = -W[(size_t)l * 286 * 128 + (size_t)281 * 128 + col];
    } else {
        int Kreal = (mode == 3) ? 260 : 128;
        if (k < Kreal) v = W[(size_t)l * Kreal * 128 + (size_t)k * 128 + col];
    }
    out[pg] = (__bf16)v;
}

// ---------------- fused prep: degree atomics + pos max ----------------
__global__ __launch_bounds__(256) void k_deg_max(const int* __restrict__ dst, const float* __restrict__ pos,
                                                 int* __restrict__ deg, unsigned* __restrict__ outmax){
    __shared__ float s[256];
    int tid = threadIdx.x;
    int e = blockIdx.x * 256 + tid;
    if (e < N_EDGES) atomicAdd(deg + dst[e], 1);
    if (blockIdx.x < N_NODES / 256){
        s[tid] = pos[blockIdx.x * 256 + tid];
        __syncthreads();
        for (int off = 128; off > 0; off >>= 1){
            if (tid < off) s[tid] = fmaxf(s[tid], s[tid + off]);
            __syncthreads();
        }
        if (tid == 0) atomicMax(outmax, __float_as_uint(s[0]));
    }
}

// ---------------- CSR build: scan + scatter (+p/invdeg fused) ----------------
__global__ __launch_bounds__(256) void k_scan1(const int* __restrict__ deg, int* __restrict__ csum){
    __shared__ int s[256];
    int c = blockIdx.x, t = threadIdx.x;
    s[t] = deg[c * 256 + t];
    __syncthreads();
    for (int o = 128; o > 0; o >>= 1){ if (t < o) s[t] += s[t + o]; __syncthreads(); }
    if (t == 0) csum[c] = s[0];
}

__global__ __launch_bounds__(256) void k_scan2(const int* __restrict__ csum, int* __restrict__ coff){
    __shared__ int s[256];
    int t = threadIdx.x;
    s[t] = csum[t];
    __syncthreads();
    for (int o = 1; o < 256; o <<= 1){
        int v = (t >= o) ? s[t - o] : 0;
        __syncthreads();
        s[t] += v;
        __syncthreads();
    }
    coff[t] = s[t] - csum[t];   // exclusive
}

__global__ __launch_bounds__(256) void k_scan3(const int* __restrict__ deg, const int* __restrict__ coff,
                                               int* __restrict__ cursor){
    __shared__ int s[256];
    int c = blockIdx.x, t = threadIdx.x;
    int d = deg[c * 256 + t];
    s[t] = d;
    __syncthreads();
    for (int o = 1; o < 256; o <<= 1){
        int v = (t >= o) ? s[t - o] : 0;
        __syncthreads();
        s[t] += v;
        __syncthreads();
    }
    cursor[c * 256 + t] = coff[c] + s[t] - d;
}

__global__ __launch_bounds__(256) void k_scatter_prep(const int* __restrict__ esrc, const int* __restrict__ edst,
                                                      int* __restrict__ cursor,
                                                      int* __restrict__ ssrcS, int* __restrict__ sdstS,
                                                      const float* __restrict__ pos, const unsigned* __restrict__ maxp,
                                                      const int* __restrict__ deg,
                                                      float* __restrict__ p, float* __restrict__ invdeg){
    int e = blockIdx.x * 256 + threadIdx.x;
    if (e < N_EDGES){
        int d = edst[e];
        int slot = atomicAdd(cursor + d, 1);
        ssrcS[slot] = esrc[e];
        sdstS[slot] = d;
    }
    if (blockIdx.x < N_NODES / 256){
        int i = blockIdx.x * 256 + threadIdx.x;
        float mp = __uint_as_float(*maxp);
        p[i] = pos[i] / mp;
        invdeg[i] = 1.0f / fmaxf((float)deg[i], 1.0f);
    }
}

// ---------------- encoder (f32, runs once) — R5-proven version ----------------
__device__ __forceinline__ void gemm44(const float* A, int lda, const float* __restrict__ W,
                                       int kq_begin, int kq_end, int r0, int c0, float acc[4][4]){
    for (int kq = kq_begin; kq < kq_end; ++kq){
        int k = kq * 4;
        float a[4][4], w[4][4];
        #pragma unroll
        for (int i = 0; i < 4; ++i){
            float4 v = *(const float4*)(A + (r0 + i) * lda + k);
            a[i][0] = v.x; a[i][1] = v.y; a[i][2] = v.z; a[i][3] = v.w;
        }
        #pragma unroll
        for (int kk = 0; kk < 4; ++kk){
            float4 v = *(const float4*)(W + (k + kk) * 128 + c0);
            w[kk][0] = v.x; w[kk][1] = v.y; w[kk][2] = v.z; w[kk][3] = v.w;
        }
        #pragma unroll
        for (int kk = 0; kk < 4; ++kk)
            #pragma unroll
            for (int i = 0; i < 4; ++i)
                #pragma unroll
                for (int j = 0; j < 4; ++j)
                    acc[i][j] = fmaf(a[i][kk], w[kk][j], acc[i][j]);
    }
}

__global__ __launch_bounds__(256) void k_enc(const float* __restrict__ x, const float* __restrict__ p,
                                             const float* __restrict__ vars,
                                             const float* __restrict__ W1, const float* __restrict__ b1,
                                             const float* __restrict__ W2, const float* __restrict__ b2,
                                             float* __restrict__ hA){
    __shared__ __align__(16) float sin_[32 * 32];
    __shared__ __align__(16) float sw1[32 * 128];
    __shared__ __align__(16) float sy[32 * 128];
    int tid = threadIdx.x;
    int n0 = blockIdx.x * 32;
    for (int i = tid; i < 32 * 32; i += 256){
        int e = i >> 5, k = i & 31;
        int node = n0 + e;
        float v;
        if (k < 25)       v = x[node * 25 + k];
        else if (k == 25) v = p[node];
        else if (k == 26) v = vars[node * 4 + 3] * (1.0f / T_MAX_F);
        else if (k < 30)  v = vars[node * 4 + (k - 27)];
        else              v = 0.0f;
        sin_[e * 32 + k] = v;
    }
    for (int i = tid; i < 32 * 128; i += 256){
        int r = i >> 7;
        sw1[i] = (r < 30) ? W1[i] : 0.0f;
    }
    __syncthreads();
    int c0 = (tid & 31) * 4, r0 = (tid >> 5) * 4;
    float acc[4][4] = {};
    gemm44(sin_, 32, sw1, 0, 8, r0, c0, acc);
    float4 bv = *(const float4*)(b1 + c0);
    float b_[4] = {bv.x, bv.y, bv.z, bv.w};
    #pragma unroll
    for (int i = 0; i < 4; ++i){
        float4 o;
        o.x = silu_f(acc[i][0] + b_[0]);
        o.y = silu_f(acc[i][1] + b_[1]);
        o.z = silu_f(acc[i][2] + b_[2]);
        o.w = silu_f(acc[i][3] + b_[3]);
        *(float4*)(sy + (r0 + i) * 128 + c0) = o;
    }
    __syncthreads();
    float acc2[4][4] = {};
    gemm44(sy, 128, W2, 0, 32, r0, c0, acc2);
    float4 b2v = *(const float4*)(b2 + c0);
    float bb[4] = {b2v.x, b2v.y, b2v.z, b2v.w};
    #pragma unroll
    for (int i = 0; i < 4; ++i){
        float4 o;
        o.x = silu_f(acc2[i][0] + bb[0]);
        o.y = silu_f(acc2[i][1] + bb[1]);
        o.z = silu_f(acc2[i][2] + bb[2]);
        o.w = silu_f(acc2[i][3] + bb[3]);
        *(float4*)(hA + (size_t)(n0 + r0 + i) * 128 + c0) = o;
    }
}

// ---------------- node precompute: inline stats + LN + ra/rb GEMM; zeroes agg + statCur ----------------
__global__ __launch_bounds__(256) void k_npre(const float* __restrict__ hA, const float* __restrict__ x,
                                              const float* __restrict__ p, const float* __restrict__ vars,
                                              const float* __restrict__ statPrev, int apply_ln,
                                              const __bf16* __restrict__ Wra, const __bf16* __restrict__ Wrb,
                                              const float* __restrict__ b1,
                                              __bf16* __restrict__ raO, __bf16* __restrict__ rbO,
                                              float* __restrict__ aggZ, float* __restrict__ statCurZ){
    __shared__ __align__(16) __bf16 sA[10 * 64 * 8];
    __shared__ __align__(16) float sOut[32 * 264];
    __shared__ __align__(16) float smu[128], sistd[128];
    int tid = threadIdx.x;
    int n0 = blockIdx.x * 32;
    if (apply_ln && tid < 128){
        float m = statPrev[tid] * (1.0f / N_NODES);
        float v = statPrev[128 + tid] * (1.0f / N_NODES) - m * m;
        smu[tid] = m;
        sistd[tid] = rsqrtf(v + EPS_F);
    }
    if (blockIdx.x == 0) statCurZ[tid] = 0.f;
    {
        float4 z4 = {0.f, 0.f, 0.f, 0.f};
        #pragma unroll
        for (int it = 0; it < 4; ++it){
            int i = tid + it * 256;
            int e = i >> 5, ch = i & 31;
            *(float4*)(aggZ + (size_t)(n0 + e) * 128 + ch * 4) = z4;
        }
    }
    __syncthreads();
    #pragma unroll
    for (int it = 0; it < 3; ++it){
        int j = tid + it * 256;
        if (j < 640){
            int f = j >> 6, lane = j & 63;
            int kb = f >> 1, mt = f & 1;
            int e = (lane & 15) + mt * 16, kh = lane >> 4;
            int node = n0 + e;
            bf16x8 o;
            if (kb < 4){
                int k0 = kb * 32 + kh * 8;
                float4 v0 = *(const float4*)(hA + (size_t)node * 128 + k0);
                float4 v1 = *(const float4*)(hA + (size_t)node * 128 + k0 + 4);
                if (apply_ln){
                    float4 m0 = *(const float4*)(smu + k0),   m1 = *(const float4*)(smu + k0 + 4);
                    float4 s0 = *(const float4*)(sistd + k0), s1 = *(const float4*)(sistd + k0 + 4);
                    v0.x = (v0.x - m0.x) * s0.x; v0.y = (v0.y - m0.y) * s0.y;
                    v0.z = (v0.z - m0.z) * s0.z; v0.w = (v0.w - m0.w) * s0.w;
                    v1.x = (v1.x - m1.x) * s1.x; v1.y = (v1.y - m1.y) * s1.y;
                    v1.z = (v1.z - m1.z) * s1.z; v1.w = (v1.w - m1.w) * s1.w;
                }
                o[0] = (__bf16)v0.x; o[1] = (__bf16)v0.y; o[2] = (__bf16)v0.z; o[3] = (__bf16)v0.w;
                o[4] = (__bf16)v1.x; o[5] = (__bf16)v1.y; o[6] = (__bf16)v1.z; o[7] = (__bf16)v1.w;
            } else {
                #pragma unroll
                for (int jj = 0; jj < 8; ++jj){
                    int fk = kh * 8 + jj;
                    float v;
                    if (fk < 25)       v = x[node * 25 + fk];
                    else if (fk == 25) v = p[node];
                    else if (fk < 30)  v = vars[node * 4 + (fk - 26)];
                    else               v = 0.0f;
                    o[jj] = (__bf16)v;
                }
            }
            *(bf16x8*)(sA + (f * 64 + lane) * 8) = o;
        }
    }
    __syncthreads();
    int w = tid >> 6, lane = tid & 63;
    int clo = lane & 15, rhi = lane >> 4;
    f32x4 z = {0.f, 0.f, 0.f, 0.f};
    f32x4 aR[2][2] = {{z, z}, {z, z}};
    f32x4 aB[2][2] = {{z, z}, {z, z}};
    #pragma unroll
    for (int kb = 0; kb < 5; ++kb){
        bf16x8 a0 = *(bf16x8*)(sA + ((kb * 2 + 0) * 64 + lane) * 8);
        bf16x8 a1 = *(bf16x8*)(sA + ((kb * 2 + 1) * 64 + lane) * 8);
        bf16x8 wr0 = *(const bf16x8*)(Wra + (size_t)((kb * 8 + 2 * w)     * 64 + lane) * 8);
        bf16x8 wr1 = *(const bf16x8*)(Wra + (size_t)((kb * 8 + 2 * w + 1) * 64 + lane) * 8);
        bf16x8 wb0 = *(const bf16x8*)(Wrb + (size_t)((kb * 8 + 2 * w)     * 64 + lane) * 8);
        bf16x8 wb1 = *(const bf16x8*)(Wrb + (size_t)((kb * 8 + 2 * w + 1) * 64 + lane) * 8);
        aR[0][0] = mfma16(a0, wr0, aR[0][0]);
        aR[0][1] = mfma16(a0, wr1, aR[0][1]);
        aR[1][0] = mfma16(a1, wr0, aR[1][0]);
        aR[1][1] = mfma16(a1, wr1, aR[1][1]);
        aB[0][0] = mfma16(a0, wb0, aB[0][0]);
        aB[0][1] = mfma16(a0, wb1, aB[0][1]);
        aB[1][0] = mfma16(a1, wb0, aB[1][0]);
        aB[1][1] = mfma16(a1, wb1, aB[1][1]);
    }
    #pragma unroll
    for (int nf = 0; nf < 2; ++nf){
        int col = (2 * w + nf) * 16 + clo;
        float bv = b1[col];
        #pragma unroll
        for (int mt = 0; mt < 2; ++mt)
            #pragma unroll
            for (int i = 0; i < 4; ++i){
                int e = mt * 16 + rhi * 4 + i;
                sOut[e * 264 + col]       = aR[mt][nf][i] + bv;
                sOut[e * 264 + 128 + col] = aB[mt][nf][i];
            }
    }
    __syncthreads();
    #pragma unroll
    for (int it = 0; it < 4; ++it){
        int j = tid + it * 256;
        int row = j >> 5, c8 = j & 31;
        const float* src = sOut + row * 264 + c8 * 8;
        bf16x8 o;
        #pragma unroll
        for (int t = 0; t < 8; ++t) o[t] = (__bf16)src[t];
        __bf16* dstp = (c8 < 16) ? (raO + (size_t)(n0 + row) * 128 + c8 * 8)
                                 : (rbO + (size_t)(n0 + row) * 128 + (c8 - 16) * 8);
        *(bf16x8*)dstp = o;
    }
}

// ---------------- edge (CSR-sorted): y1 = silu(ra[dst]+rb[src]); m = silu(y1@W2+b2);
// segmented LDS reduction by dst, one atomicAdd per (segment, col). ----------------
__global__ __launch_bounds__(256) void k_edge3(const __bf16* __restrict__ ra, const __bf16* __restrict__ rb,
                                               const int* __restrict__ ssrcS, const int* __restrict__ sdstS,
                                               const __bf16* __restrict__ Wp2, const float* __restrict__ bias2,
                                               float* __restrict__ agg){
    __shared__ __align__(16) unsigned char smem[64 * 128 * 4];
    __shared__ int sd[64], ss[64];
    __bf16* sA   = (__bf16*)smem;
    float*  msum = (float*)smem;
    int tid = threadIdx.x;
    int e0 = blockIdx.x * 64;
    if (tid < 64){ sd[tid] = sdstS[e0 + tid]; ss[tid] = ssrcS[e0 + tid]; }
    __syncthreads();
    #pragma unroll
    for (int it = 0; it < 4; ++it){
        int j = tid + it * 256;
        int f = j >> 6, lane = j & 63;
        int kb = f >> 2, mt = f & 3;
        int e = (lane & 15) + mt * 16;
        int k0 = kb * 32 + (lane >> 4) * 8;
        bf16x8 va = *(const bf16x8*)(ra + (size_t)sd[e] * 128 + k0);
        bf16x8 vb = *(const bf16x8*)(rb + (size_t)ss[e] * 128 + k0);
        bf16x8 o;
        #pragma unroll
        for (int t = 0; t < 8; ++t)
            o[t] = (__bf16)silu_f((float)va[t] + (float)vb[t]);
        *(bf16x8*)(sA + (f * 64 + lane) * 8) = o;
    }
    __syncthreads();
    int w = tid >> 6, lane = tid & 63;
    int cb0 = 2 * w, clo = lane & 15, rhi = lane >> 4;
    f32x4 z = {0.f, 0.f, 0.f, 0.f};
    f32x4 acc[4][2] = {{z, z}, {z, z}, {z, z}, {z, z}};
    #pragma unroll
    for (int kb = 0; kb < 4; ++kb){
        bf16x8 a0 = *(bf16x8*)(sA + ((kb * 4 + 0) * 64 + lane) * 8);
        bf16x8 a1 = *(bf16x8*)(sA + ((kb * 4 + 1) * 64 + lane) * 8);
        bf16x8 a2 = *(bf16x8*)(sA + ((kb * 4 + 2) * 64 + lane) * 8);
        bf16x8 a3 = *(bf16x8*)(sA + ((kb * 4 + 3) * 64 + lane) * 8);
        bf16x8 w0 = *(const bf16x8*)(Wp2 + (size_t)((kb * 8 + cb0)     * 64 + lane) * 8);
        bf16x8 w1 = *(const bf16x8*)(Wp2 + (size_t)((kb * 8 + cb0 + 1) * 64 + lane) * 8);
        acc[0][0] = mfma16(a0, w0, acc[0][0]);
        acc[0][1] = mfma16(a0, w1, acc[0][1]);
        acc[1][0] = mfma16(a1, w0, acc[1][0]);
        acc[1][1] = mfma16(a1, w1, acc[1][1]);
        acc[2][0] = mfma16(a2, w0, acc[2][0]);
        acc[2][1] = mfma16(a2, w1, acc[2][1]);
        acc[3][0] = mfma16(a3, w0, acc[3][0]);
        acc[3][1] = mfma16(a3, w1, acc[3][1]);
    }
    __syncthreads();
    #pragma unroll
    for (int nf = 0; nf < 2; ++nf){
        int col = (cb0 + nf) * 16 + clo;
        float bv = bias2[col];
        #pragma unroll
        for (int mt = 0; mt < 4; ++mt)
            #pragma unroll
            for (int i = 0; i < 4; ++i){
                int row = mt * 16 + rhi * 4 + i;
                msum[row * 128 + col] = silu_f(acc[mt][nf][i] + bv);
            }
    }
    __syncthreads();
    int col = tid & 127, half = tid >> 7;
    int base = half * 32;
    float run = 0.0f;
    for (int r = 0; r < 32; ++r){
        int row = base + r;
        run += msum[row * 128 + col];
        bool flush = (r == 31) || (sd[row + 1] != sd[row]);
        if (flush){
            atomicAdd(agg + (size_t)sd[row] * 128 + col, run);
            run = 0.0f;
        }
    }
}

// ---------------- node update MLP: M=64, fragment-direct staging, inline stats ----------------
__global__ __launch_bounds__(256) void k_upd_m(float* __restrict__ hA, const float* __restrict__ agg,
                                               const float* __restrict__ vars, const float* __restrict__ invdeg,
                                               const float* __restrict__ statPrev, int apply_ln,
                                               const __bf16* __restrict__ Wp1, const float* __restrict__ bias1,
                                               const __bf16* __restrict__ Wp2, const float* __restrict__ bias2,
                                               float* __restrict__ statCur){
    __shared__ __align__(16) __bf16 sA1[36 * 64 * 8];   // 36 KB; zb overlays after GEMM1
    __shared__ __align__(16) float smu[128], sistd[128];
    __bf16* zb = sA1;
    int tid = threadIdx.x;
    int n0 = blockIdx.x * 64;
    if (apply_ln && tid < 128){
        float m = statPrev[tid] * (1.0f / N_NODES);
        float v = statPrev[128 + tid] * (1.0f / N_NODES) - m * m;
        smu[tid] = m;
        sistd[tid] = rsqrtf(v + EPS_F);
    }
    __syncthreads();
    #pragma unroll
    for (int it = 0; it < 9; ++it){
        int idx = tid + it * 256;
        int f = idx >> 6, lane = idx & 63;
        int kb = f >> 2, mt = f & 3;
        int row = (lane & 15) + mt * 16;
        int node = n0 + row;
        int k0 = kb * 32 + ((lane >> 4) << 3);
        bf16x8 o;
        if (k0 < 128){
            float4 v0 = *(const float4*)(hA + (size_t)node * 128 + k0);
            float4 v1 = *(const float4*)(hA + (size_t)node * 128 + k0 + 4);
            if (apply_ln){
                float4 m0 = *(const float4*)(smu + k0),   m1 = *(const float4*)(smu + k0 + 4);
                float4 s0 = *(const float4*)(sistd + k0), s1 = *(const float4*)(sistd + k0 + 4);
                v0.x = (v0.x - m0.x) * s0.x; v0.y = (v0.y - m0.y) * s0.y;
                v0.z = (v0.z - m0.z) * s0.z; v0.w = (v0.w - m0.w) * s0.w;
                v1.x = (v1.x - m1.x) * s1.x; v1.y = (v1.y - m1.y) * s1.y;
                v1.z = (v1.z - m1.z) * s1.z; v1.w = (v1.w - m1.w) * s1.w;
            }
            o[0] = (__bf16)v0.x; o[1] = (__bf16)v0.y; o[2] = (__bf16)v0.z; o[3] = (__bf16)v0.w;
            o[4] = (__bf16)v1.x; o[5] = (__bf16)v1.y; o[6] = (__bf16)v1.z; o[7] = (__bf16)v1.w;
        } else if (k0 < 256){
            int g0 = k0 - 128;
            float4 v0 = *(const float4*)(agg + (size_t)node * 128 + g0);
            float4 v1 = *(const float4*)(agg + (size_t)node * 128 + g0 + 4);
            float s = invdeg[node];
            o[0] = (__bf16)(v0.x * s); o[1] = (__bf16)(v0.y * s); o[2] = (__bf16)(v0.z * s); o[3] = (__bf16)(v0.w * s);
            o[4] = (__bf16)(v1.x * s); o[5] = (__bf16)(v1.y * s); o[6] = (__bf16)(v1.z * s); o[7] = (__bf16)(v1.w * s);
        } else {
            int fk = k0 - 256;
            #pragma unroll
            for (int jj = 0; jj < 8; ++jj){
                int kk = fk + jj;
                o[jj] = (__bf16)((kk < 4) ? vars[(size_t)node * 4 + kk] : 0.0f);
            }
        }
        *(bf16x8*)(sA1 + (size_t)idx * 8) = o;
    }
    __syncthreads();
    int w = tid >> 6, lane = tid & 63;
    int cb0 = 2 * w, clo = lane & 15, rhi = lane >> 4;
    f32x4 z = {0.f, 0.f, 0.f, 0.f};
    f32x4 acc[4][2] = {{z, z}, {z, z}, {z, z}, {z, z}};
    #pragma unroll
    for (int kb = 0; kb < 9; ++kb){
        bf16x8 w0 = *(const bf16x8*)(Wp1 + (size_t)((kb * 8 + cb0)     * 64 + lane) * 8);
        bf16x8 w1 = *(const bf16x8*)(Wp1 + (size_t)((kb * 8 + cb0 + 1) * 64 + lane) * 8);
        #pragma unroll
        for (int mt = 0; mt < 4; ++mt){
            bf16x8 a = *(bf16x8*)(sA1 + ((kb * 4 + mt) * 64 + lane) * 8);
            acc[mt][0] = mfma16(a, w0, acc[mt][0]);
            acc[mt][1] = mfma16(a, w1, acc[mt][1]);
        }
    }
    __syncthreads();
    #pragma unroll
    for (int nf = 0; nf < 2; ++nf){
        int col = (cb0 + nf) * 16 + clo;
        float bv = bias1[col];
        #pragma unroll
        for (int mt = 0; mt < 4; ++mt)
            #pragma unroll
            for (int i = 0; i < 4; ++i){
                int row = mt * 16 + rhi * 4 + i;
                zb[row * 152 + col] = (__bf16)silu_f(acc[mt][nf][i] + bv);
            }
    }
    __syncthreads();
    f32x4 acc2[4][2] = {{z, z}, {z, z}, {z, z}, {z, z}};
    #pragma unroll
    for (int kb = 0; kb < 4; ++kb){
        bf16x8 w0 = *(const bf16x8*)(Wp2 + (size_t)((kb * 8 + cb0)     * 64 + lane) * 8);
        bf16x8 w1 = *(const bf16x8*)(Wp2 + (size_t)((kb * 8 + cb0 + 1) * 64 + lane) * 8);
        int k0 = kb * 32 + ((lane >> 4) << 3);
        #pragma unroll
        for (int mt = 0; mt < 4; ++mt){
            int row = (lane & 15) + mt * 16;
            bf16x8 a = *(bf16x8*)(zb + row * 152 + k0);
            acc2[mt][0] = mfma16(a, w0, acc2[mt][0]);
            acc2[mt][1] = mfma16(a, w1, acc2[mt][1]);
        }
    }
    float sm[2] = {0.f, 0.f}, sq[2] = {0.f, 0.f};
    #pragma unroll
    for (int nf = 0; nf < 2; ++nf){
        int col = (cb0 + nf) * 16 + clo;
        float bv = bias2[col];
        float muv = apply_ln ? smu[col] : 0.0f;
        float sdv = apply_ln ? sistd[col] : 1.0f;
        #pragma unroll
        for (int mt = 0; mt < 4; ++mt)
            #pragma unroll
            for (int i = 0; i < 4; ++i){
                int row = mt * 16 + rhi * 4 + i;
                size_t idx = (size_t)(n0 + row) * 128 + col;
                float u = silu_f(acc2[mt][nf][i] + bv);
                float hln = (hA[idx] - muv) * sdv;
                float hv = hln + u;
                hA[idx] = hv;
                sm[nf] += hv; sq[nf] += hv * hv;
            }
    }
    #pragma unroll
    for (int nf = 0; nf < 2; ++nf){
        float s = sm[nf], q = sq[nf];
        s += __shfl_xor(s, 16); q += __shfl_xor(q, 16);
        s += __shfl_xor(s, 32); q += __shfl_xor(q, 32);
        if (rhi == 0){
            int col = (cb0 + nf) * 16 + clo;
            atomicAdd(statCur + col, s);
            atomicAdd(statCur + 128 + col, q);
        }
    }
}

// ---------------- decoder (f32 exact): register sliding-window convs, inline stats ----------------
#define DECNB 16
__global__ __launch_bounds__(256) void k_dec(const float* __restrict__ h, const float* __restrict__ x,
                                             const float* __restrict__ dt,
                                             const float* __restrict__ W1, const float* __restrict__ b1,
                                             const float* __restrict__ W2, const float* __restrict__ b2,
                                             const float* __restrict__ statPrev,
                                             float* __restrict__ out){
    __shared__ __align__(16) float sh[DECNB * 132];
    __shared__ __align__(16) float so[DECNB * 312];
    __shared__ float pp[DECNB * 8 * 26];
    __shared__ float sw1[128], sw2[112], sb1[8];
    __shared__ __align__(16) float smu[128], sistd[128];
    int tid = threadIdx.x;
    int n0 = blockIdx.x * DECNB;
    if (tid < 128){
        float m = statPrev[tid] * (1.0f / N_NODES);
        float v = statPrev[128 + tid] * (1.0f / N_NODES) - m * m;
        smu[tid] = m;
        sistd[tid] = rsqrtf(v + EPS_F);
        sw1[tid] = W1[tid];
    } else if (tid < 240) sw2[tid - 128] = W2[tid - 128];
    if (tid < 8) sb1[tid] = b1[tid];
    __syncthreads();
    for (int i = tid; i < DECNB * 32; i += 256){
        int g = i >> 5, chunk = i & 31;
        float4 v = *(const float4*)(h + (size_t)(n0 + g) * 128 + chunk * 4);
        float4 m = *(const float4*)(smu + chunk * 4);
        float4 s = *(const float4*)(sistd + chunk * 4);
        v.x = (v.x - m.x) * s.x; v.y = (v.y - m.y) * s.y;
        v.z = (v.z - m.z) * s.z; v.w = (v.w - m.w) * s.w;
        *(float4*)(sh + g * 132 + chunk * 4) = v;
    }
    __syncthreads();
    {
        int g = tid >> 4, c = (tid >> 1) & 7, jh = tid & 1;
        int j0 = jh * 19;
        float w[16];
        #pragma unroll
        for (int k = 0; k < 16; ++k) w[k] = sw1[c * 16 + k];
        float bc = sb1[c];
        float win[16];
        #pragma unroll
        for (int k = 0; k < 16; ++k) win[k] = sh[g * 132 + 3 * j0 + k];
        #pragma unroll
        for (int j = 0; j < 19; ++j){
            float a = bc;
            #pragma unroll
            for (int k = 0; k < 16; ++k) a = fmaf(win[k], w[k], a);
            so[g * 312 + c * 38 + j0 + j] = silu_f(a);
            if (j < 18){
                #pragma unroll
                for (int k = 0; k < 13; ++k) win[k] = win[k + 3];
                int base = g * 132 + 3 * (j0 + j + 1) + 13;
                win[13] = sh[base]; win[14] = sh[base + 1]; win[15] = sh[base + 2];
            }
        }
    }
    __syncthreads();
    {
        int g = tid >> 4, c = (tid >> 1) & 7, th = tid & 1;
        int t0 = th * 13;
        int nt = th ? 12 : 13;
        float w[14];
        #pragma unroll
        for (int k = 0; k < 14; ++k) w[k] = sw2[c * 14 + k];
        float win[14];
        #pragma unroll
        for (int k = 0; k < 14; ++k) win[k] = so[g * 312 + c * 38 + t0 + k];
        #pragma unroll
        for (int t = 0; t < 13; ++t){
            if (t < nt){
                float a = 0.0f;
                #pragma unroll
                for (int k = 0; k < 14; ++k) a = fmaf(win[k], w[k], a);
                pp[(g * 8 + c) * 26 + t0 + t] = a;
            }
            if (t + 1 < nt){
                #pragma unroll
                for (int k = 0; k < 13; ++k) win[k] = win[k + 1];
                win[13] = so[g * 312 + c * 38 + t0 + t + 14];
            }
        }
    }
    __syncthreads();
    float dtv = dt[0];
    for (int i = tid; i < DECNB * 25; i += 256){
        int g = i / 25, t = i % 25;
        float a = b2[0];
        #pragma unroll
        for (int c = 0; c < 8; ++c) a += pp[(g * 8 + c) * 26 + t];
        out[(size_t)(n0 + g) * 25 + t] = x[(size_t)(n0 + g) * 25 + 24] + dtv * (float)(t + 1) * a;
    }
}

extern "C" void kernel_launch(void* const* d_in, const int* in_sizes, int n_in,
                              void* d_out, int out_size, void* d_ws, size_t ws_size,
                              hipStream_t stream){
    (void)in_sizes; (void)n_in; (void)out_size; (void)ws_size;
    const float* x      = (const float*)d_in[0];
    const float* pos    = (const float*)d_in[1];
    const float* vars   = (const float*)d_in[2];
    const float* dt     = (const float*)d_in[3];
    const int*   ei     = (const int*)d_in[4];
    const float* encW1  = (const float*)d_in[5];
    const float* encb1  = (const float*)d_in[6];
    const float* encW2  = (const float*)d_in[7];
    const float* encb2  = (const float*)d_in[8];
    const float* msgW1  = (const float*)d_in[9];
    const float* msgb1  = (const float*)d_in[10];
    const float* msgW2  = (const float*)d_in[11];
    const float* msgb2  = (const float*)d_in[12];
    const float* updW1  = (const float*)d_in[13];
    const float* updb1  = (const float*)d_in[14];
    const float* updW2  = (const float*)d_in[15];
    const float* updb2  = (const float*)d_in[16];
    const float* decW1  = (const float*)d_in[17];
    const float* decb1  = (const float*)d_in[18];
    const float* decW2  = (const float*)d_in[19];
    const float* decb2  = (const float*)d_in[20];
    float* out = (float*)d_out;

    float* ws = (float*)d_ws;
    size_t off = 0;
    float* hA      = ws + off; off += (size_t)N_NODES * 128;
    float* agg     = ws + off; off += (size_t)N_NODES * 128;
    float* sstat   = ws + off; off += 2 * 256;     // [parity][sum128|sq128]
    float* p       = ws + off; off += N_NODES;
    float* invdeg  = ws + off; off += N_NODES;
    int* deg       = (int*)(ws + off); off += N_NODES;
    unsigned* maxp = (unsigned*)(ws + off); off += 2;
    int* csum      = (int*)(ws + off); off += 256;
    int* coff      = (int*)(ws + off); off += 256;
    int* cursor    = (int*)(ws + off); off += N_NODES;
    int* ssrcS     = (int*)(ws + off); off += N_EDGES;
    int* sdstS     = (int*)(ws + off); off += N_EDGES;
    __bf16* wpack  = (__bf16*)(ws + off); off += (PK_TOTAL + 1) / 2;
    __bf16* raB    = (__bf16*)(ws + off); off += (size_t)N_NODES * 64;
    __bf16* rbB    = (__bf16*)(ws + off); off += (size_t)N_NODES * 64;

    __bf16* pra = wpack;
    __bf16* prb = pra + PK_RA;
    __bf16* pm2 = prb + PK_RB;
    __bf16* pu1 = pm2 + PK_M2;
    __bf16* pu2 = pu1 + PK_U1;

    const int* esrc = ei;
    const int* edst = ei + N_EDGES;

    hipMemsetAsync(deg, 0, (size_t)N_NODES * sizeof(int) + sizeof(unsigned), stream);

    k_pack<<<(PK_TOTAL + 255) / 256, 256, 0, stream>>>(msgW1, msgW2, updW1, updW2, wpack);
    k_deg_max<<<N_EDGES / 256, 256, 0, stream>>>(edst, pos, deg, maxp);
    k_scan1<<<256, 256, 0, stream>>>(deg, csum);
    k_scan2<<<1, 256, 0, stream>>>(csum, coff);
    k_scan3<<<256, 256, 0, stream>>>(deg, coff, cursor);
    k_scatter_prep<<<N_EDGES / 256, 256, 0, stream>>>(esrc, edst, cursor, ssrcS, sdstS,
                                                      pos, maxp, deg, p, invdeg);
    k_enc<<<N_NODES / 32, 256, 0, stream>>>(x, p, vars, encW1, encb1, encW2, encb2, hA);

    for (int l = 0; l < N_LAYERS; ++l){
        int cur = l & 1;
        float* statCur        = sstat + (size_t)cur * 256;
        const float* statPrev = sstat + (size_t)(cur ^ 1) * 256;
        k_npre<<<N_NODES / 32, 256, 0, stream>>>(hA, x, p, vars, statPrev, (l > 0) ? 1 : 0,
            pra + (size_t)l * 20480, prb + (size_t)l * 20480, msgb1 + l * 128,
            raB, rbB, agg, statCur);
        k_edge3<<<N_EDGES / 64, 256, 0, stream>>>(raB, rbB, ssrcS, sdstS,
            pm2 + (size_t)l * 16384, msgb2 + l * 128, agg);
        k_upd_m<<<N_NODES / 64, 256, 0, stream>>>(hA, agg, vars, invdeg, statPrev, (l > 0) ? 1 : 0,
            pu1 + (size_t)l * 36864, updb1 + l * 128,
            pu2 + (size_t)l * 16384, updb2 + l * 128, statCur);
    }

    k_dec<<<N_NODES / DECNB, 256, 0, stream>>>(hA, x, dt, decW1, decb1, decW2, decb2,
                                               sstat + 256, out);
}